// Round 9
// baseline (1187.765 us; speedup 1.0000x reference)
//
#include <hip/hip_runtime.h>
#include <hip/hip_fp16.h>

typedef unsigned short u16;
typedef unsigned int u32;
typedef _Float16 f16;
typedef short bf16x8 __attribute__((ext_vector_type(8)));
typedef f16 f16x8 __attribute__((ext_vector_type(8)));
typedef float f32x4 __attribute__((ext_vector_type(4)));
typedef u32 u32x4 __attribute__((ext_vector_type(4)));

#define TOKENS 16384   // B*N = 16*1024
#define CDIM 768
#define NEXP 8

// 0.125 (Dh^-0.5) * log2(e): folded into the Q plane so softmax runs in exp2
#define QSCALE 0.18033688011112043f

__device__ __forceinline__ u16 f2b(float f) {
  u32 u = __float_as_uint(f);
  return (u16)((u + 0x7fffu + ((u >> 16) & 1u)) >> 16);
}
__device__ __forceinline__ u16 f16bits(f16 x) {
  union { f16 f; u16 u; } c;
  c.f = x;
  return c.u;
}
__device__ __forceinline__ f32x4 mfma_bf(bf16x8 a, bf16x8 b, f32x4 c) {
  return __builtin_amdgcn_mfma_f32_16x16x32_bf16(a, b, c, 0, 0, 0);
}
__device__ __forceinline__ f32x4 mfma_h(f16x8 a, f16x8 b, f32x4 c) {
  return __builtin_amdgcn_mfma_f32_16x16x32_f16(a, b, c, 0, 0, 0);
}
// split 8 fp32 into f16 hi/lo planes (x = hi + lo, err ~2^-22|x|)
__device__ __forceinline__ void split8(const float* v, f16x8& h, f16x8& l) {
#pragma unroll
  for (int i = 0; i < 8; i++) {
    const f16 hh = (f16)v[i];
    h[i] = hh;
    l[i] = (f16)(v[i] - (float)hh);
  }
}

// -------------------------------------------------- transpose+split (f16)
// in: K x N fp32 -> oh/ol: N x K f16 hi/lo planes
__global__ __launch_bounds__(256) void transpose_split_f16(
    const float* __restrict__ in, f16* __restrict__ oh, f16* __restrict__ ol,
    int K, int N) {
  __shared__ float tile[64][65];
  const int n0 = blockIdx.x * 64, k0 = blockIdx.y * 64;
#pragma unroll
  for (int i = 0; i < 16; i++) {
    const int s = threadIdx.x + i * 256;
    const int r = s >> 6, c = s & 63;
    tile[r][c] = in[(size_t)(k0 + r) * N + n0 + c];
  }
  __syncthreads();
#pragma unroll
  for (int i = 0; i < 16; i++) {
    const int s = threadIdx.x + i * 256;
    const int r = s >> 6, c = s & 63;
    const float v = tile[c][r];
    const f16 h = (f16)v;
    oh[(size_t)(n0 + r) * K + k0 + c] = h;
    ol[(size_t)(n0 + r) * K + k0 + c] = (f16)(v - (float)h);
  }
}

// -------------------------------------------------- transpose (bf16, experts)
__global__ __launch_bounds__(256) void transpose_f32_bf16(
    const float* __restrict__ in, u16* __restrict__ out, int K, int N) {
  __shared__ u16 tile[64][65];
  const int z = blockIdx.z;
  in += (size_t)z * K * N;
  out += (size_t)z * K * N;
  const int n0 = blockIdx.x * 64, k0 = blockIdx.y * 64;
#pragma unroll
  for (int i = 0; i < 16; i++) {
    const int s = threadIdx.x + i * 256;
    const int r = s >> 6, c = s & 63;
    tile[r][c] = f2b(in[(size_t)(k0 + r) * N + n0 + c]);
  }
  __syncthreads();
#pragma unroll
  for (int i = 0; i < 16; i++) {
    const int s = threadIdx.x + i * 256;
    const int r = s >> 6, c = s & 63;
    out[(size_t)(n0 + r) * K + k0 + c] = tile[c][r];
  }
}

// -------------------------------------------------- layernorm
template <bool BF16OUT>
__global__ __launch_bounds__(256) void ln_rows(const float* __restrict__ in,
                                               const float* __restrict__ g,
                                               const float* __restrict__ bt,
                                               void* __restrict__ out) {
  const int row = blockIdx.x * 4 + (threadIdx.x >> 6);
  const int lane = threadIdx.x & 63;
  const size_t base = (size_t)row * CDIM;
  float v[12];
  float s = 0.f, ss = 0.f;
#pragma unroll
  for (int j = 0; j < 12; j++) {
    const int idx = lane + j * 64;
    v[j] = in[base + idx];
    s += v[j];
    ss += v[j] * v[j];
  }
#pragma unroll
  for (int m = 1; m < 64; m <<= 1) {
    s += __shfl_xor(s, m);
    ss += __shfl_xor(ss, m);
  }
  const float mean = s * (1.f / CDIM);
  const float var = ss * (1.f / CDIM) - mean * mean;
  const float rs = rsqrtf(var + 1e-5f);
#pragma unroll
  for (int j = 0; j < 12; j++) {
    const int idx = lane + j * 64;
    const float y = (v[j] - mean) * rs * g[idx] + bt[idx];
    if (BF16OUT)
      ((u16*)out)[base + idx] = f2b(y);
    else
      ((float*)out)[base + idx] = y;
  }
}

// -------------------------------------------------- f16-split GEMM
// C[M,N] = A[M,K](fp32, split in-kernel) * Bt[N,K](pre-split f16 hi/lo).
// 128x128 tile, BK=64, 4 waves 2x2, 16x16x32 f16 MFMA, 3 MFMAs per product
// (hh + hl + lh) -> ~2^-21 relative. XOR-swizzled LDS (16B granules).
// EPI 0: plain fp32 store. EPI 1: C = acc + bias[col] + xres[row,col].
// EPI 2 (qkv): store pre-split f16 planes — Q cols (n0<768, scaled by QSCALE)
//   and K cols (768<=n0<1536) planar into Oh/Ol[row*1536+col]; V cols
//   (n0>=1536) packed (hi | lo<<16) into Ov[row*768+col-1536].
template <int EPI>
__global__ __launch_bounds__(256) void gemm_f16s(
    const float* __restrict__ A, const f16* __restrict__ Bth,
    const f16* __restrict__ Btl, float* __restrict__ C, int M, int N, int K,
    const float* __restrict__ bias, const float* __restrict__ xres,
    f16* __restrict__ Oh, f16* __restrict__ Ol, u32* __restrict__ Ov) {
  __shared__ f16 Ah[128 * 64];
  __shared__ f16 Al[128 * 64];
  __shared__ f16 Bh[128 * 64];
  __shared__ f16 Bl[128 * 64];
  const int tid = threadIdx.x;
  const int lane = tid & 63, wv = tid >> 6;
  const int wr = wv >> 1, wc = wv & 1;
  const int lm = lane & 15, lq = lane >> 4;
  const int m0 = blockIdx.y * 128, n0 = blockIdx.x * 128;
  f32x4 acc[4][4];
  const f32x4 z4 = {0.f, 0.f, 0.f, 0.f};
#pragma unroll
  for (int i = 0; i < 4; i++)
#pragma unroll
    for (int j = 0; j < 4; j++) acc[i][j] = z4;

  for (int k0 = 0; k0 < K; k0 += 64) {
    __syncthreads();
#pragma unroll
    for (int i = 0; i < 4; i++) {
      const int s = tid + i * 256;
      const int r = s >> 3, g = s & 7;
      float av[8];
      *(float4*)&av[0] = *(const float4*)(A + (size_t)(m0 + r) * K + k0 + g * 8);
      *(float4*)&av[4] =
          *(const float4*)(A + (size_t)(m0 + r) * K + k0 + g * 8 + 4);
      f16x8 hh, ll;
      split8(av, hh, ll);
      const int sw = r * 64 + ((g ^ (r & 7)) << 3);
      *(f16x8*)(&Ah[sw]) = hh;
      *(f16x8*)(&Al[sw]) = ll;
      *(f16x8*)(&Bh[sw]) = *(const f16x8*)(Bth + (size_t)(n0 + r) * K + k0 + g * 8);
      *(f16x8*)(&Bl[sw]) = *(const f16x8*)(Btl + (size_t)(n0 + r) * K + k0 + g * 8);
    }
    __syncthreads();
#pragma unroll
    for (int kx = 0; kx < 8; kx += 4) {
      f16x8 afh[4], afl[4], bfh[4], bfl[4];
#pragma unroll
      for (int i = 0; i < 4; i++) {
        const int ra = wr * 64 + i * 16 + lm;
        const int aw = ra * 64 + (((ra & 7) ^ (kx + lq)) << 3);
        afh[i] = *(const f16x8*)(&Ah[aw]);
        afl[i] = *(const f16x8*)(&Al[aw]);
        const int rb = wc * 64 + i * 16 + lm;
        const int bw = rb * 64 + (((rb & 7) ^ (kx + lq)) << 3);
        bfh[i] = *(const f16x8*)(&Bh[bw]);
        bfl[i] = *(const f16x8*)(&Bl[bw]);
      }
#pragma unroll
      for (int i = 0; i < 4; i++)
#pragma unroll
        for (int j = 0; j < 4; j++) {
          acc[i][j] = mfma_h(afh[i], bfh[j], acc[i][j]);
          acc[i][j] = mfma_h(afh[i], bfl[j], acc[i][j]);
          acc[i][j] = mfma_h(afl[i], bfh[j], acc[i][j]);
        }
    }
  }
#pragma unroll
  for (int i = 0; i < 4; i++)
#pragma unroll
    for (int r = 0; r < 4; r++) {
      const size_t row = m0 + wr * 64 + i * 16 + lq * 4 + r;
#pragma unroll
      for (int j = 0; j < 4; j++) {
        const int col = n0 + wc * 64 + j * 16 + lm;
        float v = acc[i][j][r];
        if constexpr (EPI == 0) {
          C[row * N + col] = v;
        } else if constexpr (EPI == 1) {
          v += bias[col] + xres[row * N + col];
          C[row * N + col] = v;
        } else {
          // EPI 2: qkv split-store (block-uniform section: n0 is 128-aligned)
          if (n0 < 768) v *= QSCALE;  // Q pre-scale (fp32, exact math fold)
          const f16 hh = (f16)v;
          const f16 ll = (f16)(v - (float)hh);
          if (n0 < 1536) {
            Oh[row * 1536 + col] = hh;
            Ol[row * 1536 + col] = ll;
          } else {
            Ov[row * 768 + (col - 1536)] =
                (u32)f16bits(hh) | ((u32)f16bits(ll) << 16);
          }
        }
      }
    }
}

// -------------------------------------------------- f16-split flash attention
// v5: KVBLK=32 — LDS 26.6 KB (K 8K + V 10K padded-row + P 8K) -> 6 blocks/CU
// (was 48 KB / 3 blocks). Targets the measured latency-bound profile (all
// pipes <41%, occupancy 30%): doubles resident waves to overlap the serial
// QK^T->softmax->PV chains. V uses 40-f16 row pitch (2-way bank alias, free)
// instead of XOR swizzle. Q/K/V pre-split by qkv epilogue; softmax in exp2
// (QSCALE folded into Q). Output fp32 (round-6 form).
__global__ __launch_bounds__(256) void attn_f16s(
    const f16* __restrict__ qkh, const f16* __restrict__ qkl,
    const u32* __restrict__ vI, float* __restrict__ o, int qb) {
  __shared__ f16 Kh[32 * 64];
  __shared__ f16 Kl[32 * 64];
  __shared__ f16 Vh[64 * 40];
  __shared__ f16 Vl[64 * 40];
  __shared__ f16 Ph[4 * 16 * 32];
  __shared__ f16 Pl[4 * 16 * 32];
  const int bz = blockIdx.z, h = blockIdx.y, qt = blockIdx.x;
  const int tid = threadIdx.x, wv = tid >> 6, lane = tid & 63;
  const int lm = lane & 15, lq = lane >> 4;

  // Q fragments (A-layout): rows wv*16+lm, k = frag*32 + lq*8 .. +8
  f16x8 qh[2], ql[2];
  {
    const size_t qrow =
        (size_t)(bz * 1024 + qt * 64 + wv * 16 + lm) * 1536 + h * 64;
#pragma unroll
    for (int f = 0; f < 2; f++) {
      qh[f] = *(const f16x8*)(qkh + qrow + f * 32 + lq * 8);
      ql[f] = *(const f16x8*)(qkl + qrow + f * 32 + lq * 8);
    }
  }
  const f32x4 z4 = {0.f, 0.f, 0.f, 0.f};
  f32x4 oacc[4];
#pragma unroll
  for (int jb = 0; jb < 4; jb++) oacc[jb] = z4;
  float mrun[4], lrun[4];
#pragma unroll
  for (int r = 0; r < 4; r++) {
    mrun[r] = -1e30f;
    lrun[r] = 0.f;
  }
  // staging geometry: K row kr=tid>>3 (0..31), granule kg=tid&7;
  // V: dim vd=tid&63 (row of Vt), key-group vkg=tid>>6 (keys vkg*8..+8)
  const int kr = tid >> 3, kg = tid & 7;
  const int ksw = kr * 64 + ((kg ^ (kr & 7)) << 3);
  const int vd = tid & 63;
  const int vkg = tid >> 6;
  f16* pwh = &Ph[wv * 16 * 32];
  f16* pwl = &Pl[wv * 16 * 32];

  for (int kt = 0; kt < 32; kt++) {
    __syncthreads();
    // stage K tile (32 keys x 64 dims) hi/lo from planes, swizzled
    {
      const size_t kb =
          (size_t)(bz * 1024 + kt * 32 + kr) * 1536 + 768 + h * 64 + kg * 8;
      *(f16x8*)(&Kh[ksw]) = *(const f16x8*)(qkh + kb);
      *(f16x8*)(&Kl[ksw]) = *(const f16x8*)(qkl + kb);
    }
    // stage V transposed: Vt[dim][key], 40-f16 row pitch, u32 bit-unpack
    {
      f16x8 hh, ll;
#pragma unroll
      for (int j = 0; j < 8; j++) {
        const u32 w = vI[(size_t)(bz * 1024 + kt * 32 + vkg * 8 + j) * 768 +
                         h * 64 + vd];
        ((u16*)&hh)[j] = (u16)(w & 0xffffu);
        ((u16*)&ll)[j] = (u16)(w >> 16);
      }
      const int sw = vd * 40 + vkg * 8;
      *(f16x8*)(&Vh[sw]) = hh;
      *(f16x8*)(&Vl[sw]) = ll;
    }
    __syncthreads();

    // S' = Q' K^T (pre-scaled; 16 q-rows x 32 keys), f16-split
    f32x4 sa[2];
#pragma unroll
    for (int j = 0; j < 2; j++) sa[j] = z4;
#pragma unroll
    for (int kx = 0; kx < 8; kx += 4) {
      const f16x8 ah = qh[kx >> 2], al = ql[kx >> 2];
#pragma unroll
      for (int j = 0; j < 2; j++) {
        const int rb = j * 16 + lm;
        const int bw = rb * 64 + (((rb & 7) ^ (kx + lq)) << 3);
        const f16x8 bh = *(const f16x8*)(&Kh[bw]);
        const f16x8 bl = *(const f16x8*)(&Kl[bw]);
        sa[j] = mfma_h(ah, bh, sa[j]);
        sa[j] = mfma_h(ah, bl, sa[j]);
        sa[j] = mfma_h(al, bh, sa[j]);
      }
    }

    // online softmax per q-row in base-2 (scale folded into Q)
#pragma unroll
    for (int r = 0; r < 4; r++) {
      float mx = fmaxf(sa[0][r], sa[1][r]);
      mx = fmaxf(mx, __shfl_xor(mx, 1));
      mx = fmaxf(mx, __shfl_xor(mx, 2));
      mx = fmaxf(mx, __shfl_xor(mx, 4));
      mx = fmaxf(mx, __shfl_xor(mx, 8));
      const float mnew = fmaxf(mrun[r], mx);
      const float alpha = exp2f(mrun[r] - mnew);
      float ps = 0.f;
#pragma unroll
      for (int j = 0; j < 2; j++) {
        const float p = exp2f(sa[j][r] - mnew);
        sa[j][r] = p;
        ps += p;
      }
      ps += __shfl_xor(ps, 1);
      ps += __shfl_xor(ps, 2);
      ps += __shfl_xor(ps, 4);
      ps += __shfl_xor(ps, 8);
      lrun[r] = lrun[r] * alpha + ps;
      mrun[r] = mnew;
#pragma unroll
      for (int jb = 0; jb < 4; jb++) oacc[jb][r] *= alpha;
    }

    // P: C-layout -> per-wave LDS (A-layout roundtrip), split hi/lo
#pragma unroll
    for (int j = 0; j < 2; j++)
#pragma unroll
      for (int r = 0; r < 4; r++) {
        const int qr = lq * 4 + r;
        const int key = j * 16 + lm;
        const int ad = qr * 32 + (((qr & 3) ^ (key >> 3)) << 3) + (key & 7);
        const float p = sa[j][r];
        const f16 ph = (f16)p;
        pwh[ad] = ph;
        pwl[ad] = (f16)(p - (float)ph);
      }
    // O += P V, f16-split (keys = 32 = one MFMA K-pass)
    {
      const int pw = lm * 32 + (((lm & 3) ^ lq) << 3);
      const f16x8 pah = *(const f16x8*)(&pwh[pw]);
      const f16x8 pal = *(const f16x8*)(&pwl[pw]);
#pragma unroll
      for (int jb = 0; jb < 4; jb++) {
        const int vw = (jb * 16 + lm) * 40 + lq * 8;
        const f16x8 vh = *(const f16x8*)(&Vh[vw]);
        const f16x8 vl = *(const f16x8*)(&Vl[vw]);
        oacc[jb] = mfma_h(pah, vh, oacc[jb]);
        oacc[jb] = mfma_h(pah, vl, oacc[jb]);
        oacc[jb] = mfma_h(pal, vh, oacc[jb]);
      }
    }
  }
  const int gtok = (qb * 4 + bz) * 1024 + qt * 64;
#pragma unroll
  for (int r = 0; r < 4; r++) {
    const float inv = 1.f / lrun[r];
    const size_t row = (size_t)gtok + wv * 16 + lq * 4 + r;
#pragma unroll
    for (int jb = 0; jb < 4; jb++) {
      const int col = h * 64 + jb * 16 + lm;
      o[row * CDIM + col] = oacc[jb][r] * inv;
    }
  }
}

// -------------------------------------------------- bf16 expert GEMM
// v3: no atomics. 1-D grid (6144 blocks), did&7 = expert = XCD (round-robin
// dispatch) so each XCD's L2 holds exactly one expert's B panel + its A rows.
// Output: weighted f16 rows plain-stored into compact C_perm[32768][768]
// (lives in d_out), row = eBase[e] + rowi. 2-phase reg prefetch kept.
__global__ __launch_bounds__(256) void gemm_expert(
    const u16* __restrict__ A, const u16* __restrict__ Bt,
    __half* __restrict__ Cp, int N, int K, const float* __restrict__ bias,
    const int* __restrict__ counts, const int* __restrict__ eBase,
    const int* __restrict__ tokList, const float* __restrict__ wgtList) {
  __shared__ u16 As[128 * 64];
  __shared__ u16 Bs[128 * 64];
  const int did = blockIdx.x;
  const int e = did & 7;        // expert pinned to XCD
  const int s = did >> 3;       // 0..767 within expert
  const int bx = s % 6;         // n-block
  const int by = s / 6;         // m-panel (real work front-loaded per XCD)
  const int cnt = counts[e];
  const int m0 = by * 128, n0 = bx * 128;
  if (m0 >= cnt) return;
  const int tid = threadIdx.x;
  const int lane = tid & 63, wv = tid >> 6;
  const int wr = wv >> 1, wc = wv & 1;
  const int lm = lane & 15, lq = lane >> 4;
  const u16* Bte = Bt + (size_t)e * N * K;
  const int* tokl = tokList + e * TOKENS;
  const float* wl = wgtList + e * TOKENS;
  const float* biasE = bias + e * N;
  const int base0 = eBase[e];

  // hoisted staging geometry: thread stages A/B rows r0 + {0,32,64,96}
  const int r0 = tid >> 3, g = tid & 7;
  const int swz = (g ^ (r0 & 7)) << 3;  // (r0+i*32)&7 == r0&7
  const u16* ap[4];
  const u16* bp[4];
#pragma unroll
  for (int i = 0; i < 4; i++) {
    const int row = m0 + r0 + i * 32;
    const int tok = (row < cnt) ? tokl[row] : 0;
    ap[i] = A + (size_t)tok * K + g * 8;
    bp[i] = Bte + (size_t)(n0 + r0 + i * 32) * K + g * 8;
  }

  f32x4 acc[4][4];
  const f32x4 z4 = {0.f, 0.f, 0.f, 0.f};
#pragma unroll
  for (int i = 0; i < 4; i++)
#pragma unroll
    for (int j = 0; j < 4; j++) acc[i][j] = z4;

  // prologue: tile 0 -> regs -> LDS
  u32x4 pa[4], pb[4];
#pragma unroll
  for (int i = 0; i < 4; i++) {
    pa[i] = *(const u32x4*)(ap[i]);
    pb[i] = *(const u32x4*)(bp[i]);
  }
#pragma unroll
  for (int i = 0; i < 4; i++) {
    *(u32x4*)(&As[(r0 + i * 32) * 64 + swz]) = pa[i];
    *(u32x4*)(&Bs[(r0 + i * 32) * 64 + swz]) = pb[i];
  }

  for (int k0 = 0; k0 < K; k0 += 64) {
    __syncthreads();  // LDS tile k0 ready
    const bool more = (k0 + 64) < K;
    if (more) {
#pragma unroll
      for (int i = 0; i < 4; i++) {
        pa[i] = *(const u32x4*)(ap[i] + k0 + 64);
        pb[i] = *(const u32x4*)(bp[i] + k0 + 64);
      }
    }
#pragma unroll
    for (int kx = 0; kx < 8; kx += 4) {
      bf16x8 af[4], bfv[4];
#pragma unroll
      for (int i = 0; i < 4; i++) {
        const int ra = wr * 64 + i * 16 + lm;
        af[i] = *(const bf16x8*)(&As[ra * 64 + (((ra & 7) ^ (kx + lq)) << 3)]);
        const int rb = wc * 64 + i * 16 + lm;
        bfv[i] = *(const bf16x8*)(&Bs[rb * 64 + (((rb & 7) ^ (kx + lq)) << 3)]);
      }
#pragma unroll
      for (int i = 0; i < 4; i++)
#pragma unroll
        for (int j = 0; j < 4; j++)
          acc[i][j] = mfma_bf(af[i], bfv[j], acc[i][j]);
    }
    __syncthreads();  // all waves done reading LDS tile k0
    if (more) {
#pragma unroll
      for (int i = 0; i < 4; i++) {
        *(u32x4*)(&As[(r0 + i * 32) * 64 + swz]) = pa[i];
        *(u32x4*)(&Bs[(r0 + i * 32) * 64 + swz]) = pb[i];
      }
    }
  }
#pragma unroll
  for (int i = 0; i < 4; i++)
#pragma unroll
    for (int r = 0; r < 4; r++) {
      const int rowi = m0 + wr * 64 + i * 16 + lq * 4 + r;
      const bool live = (rowi < cnt);
      const float w = live ? wl[rowi] : 0.f;
      const size_t prow = live ? (size_t)(base0 + rowi) * (size_t)N : 0;
#pragma unroll
      for (int j = 0; j < 4; j++) {
        const int col = n0 + wc * 64 + j * 16 + lm;
        const float v = (acc[i][j][r] + biasE[col]) * w;
        // pair lanes: even lm stores (col, col+1) as one __half2
        const float vn = __shfl_xor(v, 1);
        if (live && (lm & 1) == 0) {
          *(__half2*)(Cp + prow + col) =
              __halves2half2(__float2half(v), __float2half(vn));
        }
      }
    }
}

// -------------------------------------------------- router (all fp32)
__global__ __launch_bounds__(256) void router_kernel(
    const float* __restrict__ x2, const float* __restrict__ g2,
    const float* __restrict__ b2, const float* __restrict__ rw,
    const float* __restrict__ rb, const float* __restrict__ rlng,
    const float* __restrict__ rlnb, const float* __restrict__ noise,
    int* __restrict__ eidx, float* __restrict__ ewgt) {
  const int token = blockIdx.x * 4 + (threadIdx.x >> 6);
  const int lane = threadIdx.x & 63;
  const size_t base = (size_t)token * CDIM;
  float v[12];
  float s = 0.f, ss = 0.f;
#pragma unroll
  for (int j = 0; j < 12; j++) {
    const int idx = lane + j * 64;
    v[j] = x2[base + idx];
    s += v[j];
    ss += v[j] * v[j];
  }
#pragma unroll
  for (int m = 1; m < 64; m <<= 1) {
    s += __shfl_xor(s, m);
    ss += __shfl_xor(ss, m);
  }
  const float mean = s * (1.f / CDIM);
  const float var = ss * (1.f / CDIM) - mean * mean;
  const float rs = rsqrtf(var + 1e-5f);

  float acc[8];
#pragma unroll
  for (int e = 0; e < 8; e++) acc[e] = 0.f;
#pragma unroll
  for (int j = 0; j < 12; j++) {
    const int d = lane + j * 64;
    const float hv = (v[j] - mean) * rs * g2[d] + b2[d];
    const f32x4 w0v = *(const f32x4*)(rw + (size_t)d * 8);
    const f32x4 w1v = *(const f32x4*)(rw + (size_t)d * 8 + 4);
#pragma unroll
    for (int e = 0; e < 4; e++) {
      acc[e] += hv * w0v[e];
      acc[e + 4] += hv * w1v[e];
    }
  }
#pragma unroll
  for (int m = 1; m < 64; m <<= 1)
#pragma unroll
    for (int e = 0; e < 8; e++) acc[e] += __shfl_xor(acc[e], m);

  float y[8];
  float emean = 0.f;
#pragma unroll
  for (int e = 0; e < 8; e++) {
    y[e] = acc[e] + rb[e];
    emean += y[e];
  }
  emean *= 0.125f;
  float evar = 0.f;
#pragma unroll
  for (int e = 0; e < 8; e++) {
    const float d = y[e] - emean;
    evar += d * d;
  }
  evar *= 0.125f;
  const float ers = rsqrtf(evar + 1e-5f);
  float lg[8];
  float mx = -1e30f;
#pragma unroll
  for (int e = 0; e < 8; e++) {
    lg[e] = (y[e] - emean) * ers * rlng[e] + rlnb[e];
    mx = fmaxf(mx, lg[e]);
  }
  float se = 0.f;
#pragma unroll
  for (int e = 0; e < 8; e++) {
    lg[e] = expf(lg[e] - mx);
    se += lg[e];
  }
  const float inv = 1.f / se;
  float r2[8];
#pragma unroll
  for (int e = 0; e < 8; e++)
    r2[e] = lg[e] * inv + noise[(size_t)token * 8 + e] * 0.125f;

  int e0 = 0;
  float v0 = r2[0];
#pragma unroll
  for (int e = 1; e < 8; e++)
    if (r2[e] > v0) {
      v0 = r2[e];
      e0 = e;
    }
  int e1 = -1;
  float v1 = -1e30f;
#pragma unroll
  for (int e = 0; e < 8; e++)
    if (e != e0 && r2[e] > v1) {
      v1 = r2[e];
      e1 = e;
    }
  const float w0 = 1.f / (1.f + expf(v1 - v0));
  if (lane == 0) {
    eidx[token * 2] = e0;
    eidx[token * 2 + 1] = e1;
    ewgt[token * 2] = w0;
    ewgt[token * 2 + 1] = 1.f - w0;
  }
}

// -------------------------------------------------- lists (+ inverse pos map)
__global__ __launch_bounds__(256) void build_lists(
    const int* __restrict__ eidx, const float* __restrict__ ewgt,
    int* __restrict__ counts, int* __restrict__ tokL, float* __restrict__ wgtL,
    int* __restrict__ posL) {
  const int e = blockIdx.x;
  __shared__ int cnt;
  if (threadIdx.x == 0) cnt = 0;
  __syncthreads();
  const int lane = threadIdx.x & 63;
  for (int t = threadIdx.x; t < TOKENS; t += 256) {
#pragma unroll
    for (int k = 0; k < 2; k++) {
      const bool match = (eidx[t * 2 + k] == e);
      const unsigned long long mb = __ballot(match);
      if (mb) {
        const int leader = __ffsll((unsigned long long)mb) - 1;
        int base = 0;
        if (lane == leader) base = atomicAdd(&cnt, __popcll(mb));
        base = __shfl(base, leader);
        if (match) {
          const int rank = __popcll(mb & ((1ull << lane) - 1ull));
          tokL[e * TOKENS + base + rank] = t;
          wgtL[e * TOKENS + base + rank] = ewgt[t * 2 + k];
          posL[t * 2 + k] = base + rank;
        }
      }
    }
  }
  __syncthreads();
  if (threadIdx.x == 0) counts[e] = cnt;
}

// -------------------------------------------------- prefix over 8 counts
__global__ void prefix_counts(const int* __restrict__ counts,
                              int* __restrict__ eBase) {
  if (threadIdx.x == 0) {
    int s = 0;
#pragma unroll
    for (int e = 0; e < NEXP; e++) {
      eBase[e] = s;
      s += counts[e];
    }
    eBase[NEXP] = s;
  }
}

// -------------------------------------------------- combine: x2 += moe rows
__global__ __launch_bounds__(256) void combine_moe(
    float* __restrict__ x2, const __half* __restrict__ Cp,
    const int* __restrict__ eidx, const int* __restrict__ posL,
    const int* __restrict__ eBase) {
  const int t = blockIdx.x * 4 + (threadIdx.x >> 6);
  const int lane = threadIdx.x & 63;
  const int e0 = eidx[t * 2], e1 = eidx[t * 2 + 1];
  const size_t q0 = (size_t)(eBase[e0] + posL[t * 2]) * CDIM;
  const size_t q1 = (size_t)(eBase[e1] + posL[t * 2 + 1]) * CDIM;
  const size_t base = (size_t)t * CDIM;
#pragma unroll
  for (int j = 0; j < 12; j++) {
    const int d = lane + j * 64;
    const float m =
        __half2float(Cp[q0 + d]) + __half2float(Cp[q1 + d]);
    x2[base + d] += m;
  }
}

// -------------------------------------------------- copy
__global__ __launch_bounds__(256) void copy_f32(const float* __restrict__ in,
                                                float* __restrict__ out) {
  const int i = (blockIdx.x * 256 + threadIdx.x) * 4;
  *(float4*)(out + i) = *(const float4*)(in + i);
}

// -------------------------------------------------- launch
extern "C" void kernel_launch(void* const* d_in, const int* in_sizes, int n_in,
                              void* d_out, int out_size, void* d_ws,
                              size_t ws_size, hipStream_t stream) {
  const float* x = (const float*)d_in[0];
  const float* noise = (const float*)d_in[1];
  const float* ln1_g = (const float*)d_in[2];
  const float* ln1_b = (const float*)d_in[3];
  const float* qkv_w = (const float*)d_in[4];
  const float* proj_w = (const float*)d_in[5];
  const float* proj_b = (const float*)d_in[6];
  const float* ln2_g = (const float*)d_in[7];
  const float* ln2_b = (const float*)d_in[8];
  const float* route_w = (const float*)d_in[9];
  const float* route_b = (const float*)d_in[10];
  const float* rln_g = (const float*)d_in[11];
  const float* rln_b = (const float*)d_in[12];
  const float* expert_w = (const float*)d_in[13];
  const float* expert_b = (const float*)d_in[14];

  char* ws = (char*)d_ws;
  // [0, 50331648)            x2f fp32 (residual + accumulation target)
  // [50331648, 88080384)     qkv split planes for the active quarter:
  //   qkh  [4096][1536] f16  @ +50331648  (12582912 B)  Q|K hi
  //   qkl  [4096][1536] f16  @ +62914560  (12582912 B)  Q|K lo
  //   vIq  [4096][768]  u32  @ +75497472  (12582912 B)  V hi|lo packed
  // post-attn this region is reused for exp_wt + h2 + lists
  float* x2f = (float*)(ws);
  f16* qkh = (f16*)(ws + 50331648);
  f16* qkl = (f16*)(ws + 62914560);
  u32* vIq = (u32*)(ws + 75497472);
  u16* exp_wt = (u16*)(ws + 50331648);    // 9437184 (post-attn)
  u16* h2 = (u16*)(ws + 59768832);        // 25165824 (post-attn)
  int* counts = (int*)(ws + 84934656);    // 64
  int* eBase = (int*)(ws + 84934784);     // 64 (within counts' 256-B slot)
  int* eidx = (int*)(ws + 84934912);      // 131072
  float* ewgt = (float*)(ws + 85065984);  // 131072
  int* tokL = (int*)(ws + 85197056);      // 524288
  float* wgtL = (float*)(ws + 85721344);  // 524288
  int* posL = (int*)(ws + 86245632);      // 131072 -> end 86376704
  // weight f16 planes (persist until proj gemm; disjoint from qkv region)
  f16* qkvw_h = (f16*)(ws + 88080384);    // 3538944
  f16* qkvw_l = (f16*)(ws + 91619328);    // 3538944
  f16* projw_h = (f16*)(ws + 95158272);   // 1179648
  f16* projw_l = (f16*)(ws + 96337920);   // 1179648  -> end 97517568
  // h1f (post-LN1) and attention output ping-pong through d_out (fp32).
  // Post-proj, d_out is reused as C_perm: 32768 x 768 f16 = out_size exactly.
  float* h1f = (float*)d_out;
  __half* cperm = (__half*)d_out;

  const dim3 blk(256);
  transpose_split_f16<<<dim3(36, 12), blk, 0, stream>>>(qkv_w, qkvw_h, qkvw_l,
                                                        768, 2304);
  transpose_split_f16<<<dim3(12, 12), blk, 0, stream>>>(proj_w, projw_h,
                                                        projw_l, 768, 768);
  ln_rows<false><<<dim3(4096), blk, 0, stream>>>(x, ln1_g, ln1_b, h1f);
  for (int q = 0; q < 4; q++) {
    gemm_f16s<2><<<dim3(18, 32), blk, 0, stream>>>(
        h1f + (size_t)q * 4096 * 768, qkvw_h, qkvw_l, nullptr, 4096, 2304,
        768, nullptr, nullptr, qkh, qkl, vIq);
    attn_f16s<<<dim3(16, 12, 4), blk, 0, stream>>>(qkh, qkl, vIq, h1f, q);
  }
  gemm_f16s<1><<<dim3(6, 128), blk, 0, stream>>>(h1f, projw_h, projw_l, x2f,
                                                 16384, 768, 768, proj_b, x,
                                                 nullptr, nullptr, nullptr);
  ln_rows<true><<<dim3(4096), blk, 0, stream>>>(x2f, ln2_g, ln2_b, h2);
  transpose_f32_bf16<<<dim3(12, 12, 8), blk, 0, stream>>>(expert_w, exp_wt,
                                                          768, 768);
  router_kernel<<<dim3(4096), blk, 0, stream>>>(x2f, ln2_g, ln2_b, route_w,
                                                route_b, rln_g, rln_b, noise,
                                                eidx, ewgt);
  build_lists<<<dim3(8), blk, 0, stream>>>(eidx, ewgt, counts, tokL, wgtL,
                                           posL);
  prefix_counts<<<dim3(1), dim3(64), 0, stream>>>(counts, eBase);
  gemm_expert<<<dim3(6144), blk, 0, stream>>>(h2, exp_wt, cperm, 768, 768,
                                              expert_b, counts, eBase, tokL,
                                              wgtL);
  combine_moe<<<dim3(4096), blk, 0, stream>>>(x2f, cperm, eidx, posL, eBase);
  copy_f32<<<dim3(12288), blk, 0, stream>>>(x2f, (float*)d_out);
}

// Round 10
// 1126.668 us; speedup vs baseline: 1.0542x; 1.0542x over previous
//
#include <hip/hip_runtime.h>
#include <hip/hip_fp16.h>

typedef unsigned short u16;
typedef unsigned int u32;
typedef _Float16 f16;
typedef short bf16x8 __attribute__((ext_vector_type(8)));
typedef f16 f16x8 __attribute__((ext_vector_type(8)));
typedef float f32x4 __attribute__((ext_vector_type(4)));
typedef u32 u32x4 __attribute__((ext_vector_type(4)));

#define TOKENS 16384   // B*N = 16*1024
#define CDIM 768
#define NEXP 8

// 0.125 (Dh^-0.5) * log2(e): folded into the Q plane so softmax runs in exp2
#define QSCALE 0.18033688011112043f

__device__ __forceinline__ u16 f2b(float f) {
  u32 u = __float_as_uint(f);
  return (u16)((u + 0x7fffu + ((u >> 16) & 1u)) >> 16);
}
__device__ __forceinline__ u16 f16bits(f16 x) {
  union { f16 f; u16 u; } c;
  c.f = x;
  return c.u;
}
__device__ __forceinline__ f32x4 mfma_bf(bf16x8 a, bf16x8 b, f32x4 c) {
  return __builtin_amdgcn_mfma_f32_16x16x32_bf16(a, b, c, 0, 0, 0);
}
__device__ __forceinline__ f32x4 mfma_h(f16x8 a, f16x8 b, f32x4 c) {
  return __builtin_amdgcn_mfma_f32_16x16x32_f16(a, b, c, 0, 0, 0);
}
// split 8 fp32 into f16 hi/lo planes (x = hi + lo, err ~2^-22|x|)
__device__ __forceinline__ void split8(const float* v, f16x8& h, f16x8& l) {
#pragma unroll
  for (int i = 0; i < 8; i++) {
    const f16 hh = (f16)v[i];
    h[i] = hh;
    l[i] = (f16)(v[i] - (float)hh);
  }
}

// -------------------------------------------------- transpose+split (f16)
// in: K x N fp32 -> oh/ol: N x K f16 hi/lo planes
__global__ __launch_bounds__(256) void transpose_split_f16(
    const float* __restrict__ in, f16* __restrict__ oh, f16* __restrict__ ol,
    int K, int N) {
  __shared__ float tile[64][65];
  const int n0 = blockIdx.x * 64, k0 = blockIdx.y * 64;
#pragma unroll
  for (int i = 0; i < 16; i++) {
    const int s = threadIdx.x + i * 256;
    const int r = s >> 6, c = s & 63;
    tile[r][c] = in[(size_t)(k0 + r) * N + n0 + c];
  }
  __syncthreads();
#pragma unroll
  for (int i = 0; i < 16; i++) {
    const int s = threadIdx.x + i * 256;
    const int r = s >> 6, c = s & 63;
    const float v = tile[c][r];
    const f16 h = (f16)v;
    oh[(size_t)(n0 + r) * K + k0 + c] = h;
    ol[(size_t)(n0 + r) * K + k0 + c] = (f16)(v - (float)h);
  }
}

// -------------------------------------------------- transpose (bf16, experts)
__global__ __launch_bounds__(256) void transpose_f32_bf16(
    const float* __restrict__ in, u16* __restrict__ out, int K, int N) {
  __shared__ u16 tile[64][65];
  const int z = blockIdx.z;
  in += (size_t)z * K * N;
  out += (size_t)z * K * N;
  const int n0 = blockIdx.x * 64, k0 = blockIdx.y * 64;
#pragma unroll
  for (int i = 0; i < 16; i++) {
    const int s = threadIdx.x + i * 256;
    const int r = s >> 6, c = s & 63;
    tile[r][c] = f2b(in[(size_t)(k0 + r) * N + n0 + c]);
  }
  __syncthreads();
#pragma unroll
  for (int i = 0; i < 16; i++) {
    const int s = threadIdx.x + i * 256;
    const int r = s >> 6, c = s & 63;
    out[(size_t)(n0 + r) * K + k0 + c] = tile[c][r];
  }
}

// -------------------------------------------------- layernorm
template <bool BF16OUT>
__global__ __launch_bounds__(256) void ln_rows(const float* __restrict__ in,
                                               const float* __restrict__ g,
                                               const float* __restrict__ bt,
                                               void* __restrict__ out) {
  const int row = blockIdx.x * 4 + (threadIdx.x >> 6);
  const int lane = threadIdx.x & 63;
  const size_t base = (size_t)row * CDIM;
  float v[12];
  float s = 0.f, ss = 0.f;
#pragma unroll
  for (int j = 0; j < 12; j++) {
    const int idx = lane + j * 64;
    v[j] = in[base + idx];
    s += v[j];
    ss += v[j] * v[j];
  }
#pragma unroll
  for (int m = 1; m < 64; m <<= 1) {
    s += __shfl_xor(s, m);
    ss += __shfl_xor(ss, m);
  }
  const float mean = s * (1.f / CDIM);
  const float var = ss * (1.f / CDIM) - mean * mean;
  const float rs = rsqrtf(var + 1e-5f);
#pragma unroll
  for (int j = 0; j < 12; j++) {
    const int idx = lane + j * 64;
    const float y = (v[j] - mean) * rs * g[idx] + bt[idx];
    if (BF16OUT)
      ((u16*)out)[base + idx] = f2b(y);
    else
      ((float*)out)[base + idx] = y;
  }
}

// -------------------------------------------------- f16-split GEMM
// C[M,N] = A[M,K](fp32, split in-kernel) * Bt[N,K](pre-split f16 hi/lo).
// 128x128 tile, 4 waves 2x2, 16x16x32 f16 MFMA, 3 MFMAs per product
// (hh + hl + lh) -> ~2^-21 relative.
// v2: BK=32 — LDS 32 KB (was 64 KB) -> 4-5 blocks/CU (was 2). FP sequence
// identical to BK=64 (same 32-elem k-chunks, same order) -> bit-identical C.
// 64B LDS rows; granule swizzle g ^ (r&3) ^ ((r>>2)&3) balances bank quads
// for the 16-row x 4-granule wave access (r<->r+4 alias of naive fold fixed).
// EPI 0: plain fp32 store. EPI 1: C = acc + bias[col] + xres[row,col].
// EPI 2 (qkv): store pre-split f16 planes — Q cols (n0<768, scaled by QSCALE)
//   and K cols (768<=n0<1536) planar into Oh/Ol[row*1536+col]; V cols
//   (n0>=1536) packed (hi | lo<<16) into Ov[row*768+col-1536].
template <int EPI>
__global__ __launch_bounds__(256) void gemm_f16s(
    const float* __restrict__ A, const f16* __restrict__ Bth,
    const f16* __restrict__ Btl, float* __restrict__ C, int M, int N, int K,
    const float* __restrict__ bias, const float* __restrict__ xres,
    f16* __restrict__ Oh, f16* __restrict__ Ol, u32* __restrict__ Ov) {
  __shared__ f16 Ah[128 * 32];
  __shared__ f16 Al[128 * 32];
  __shared__ f16 Bh[128 * 32];
  __shared__ f16 Bl[128 * 32];
  const int tid = threadIdx.x;
  const int lane = tid & 63, wv = tid >> 6;
  const int wr = wv >> 1, wc = wv & 1;
  const int lm = lane & 15, lq = lane >> 4;
  const int m0 = blockIdx.y * 128, n0 = blockIdx.x * 128;
  f32x4 acc[4][4];
  const f32x4 z4 = {0.f, 0.f, 0.f, 0.f};
#pragma unroll
  for (int i = 0; i < 4; i++)
#pragma unroll
    for (int j = 0; j < 4; j++) acc[i][j] = z4;

  for (int k0 = 0; k0 < K; k0 += 32) {
    __syncthreads();
#pragma unroll
    for (int i = 0; i < 2; i++) {
      const int s = tid + i * 256;
      const int r = s >> 2, g = s & 3;  // row 0..127, 8-elem granule 0..3
      float av[8];
      *(float4*)&av[0] = *(const float4*)(A + (size_t)(m0 + r) * K + k0 + g * 8);
      *(float4*)&av[4] =
          *(const float4*)(A + (size_t)(m0 + r) * K + k0 + g * 8 + 4);
      f16x8 hh, ll;
      split8(av, hh, ll);
      const int sw = r * 32 + ((g ^ (r & 3) ^ ((r >> 2) & 3)) << 3);
      *(f16x8*)(&Ah[sw]) = hh;
      *(f16x8*)(&Al[sw]) = ll;
      *(f16x8*)(&Bh[sw]) = *(const f16x8*)(Bth + (size_t)(n0 + r) * K + k0 + g * 8);
      *(f16x8*)(&Bl[sw]) = *(const f16x8*)(Btl + (size_t)(n0 + r) * K + k0 + g * 8);
    }
    __syncthreads();
    {
      f16x8 afh[4], afl[4], bfh[4], bfl[4];
#pragma unroll
      for (int i = 0; i < 4; i++) {
        const int ra = wr * 64 + i * 16 + lm;
        const int aw = ra * 32 + ((lq ^ (ra & 3) ^ ((ra >> 2) & 3)) << 3);
        afh[i] = *(const f16x8*)(&Ah[aw]);
        afl[i] = *(const f16x8*)(&Al[aw]);
        const int rb = wc * 64 + i * 16 + lm;
        const int bw = rb * 32 + ((lq ^ (rb & 3) ^ ((rb >> 2) & 3)) << 3);
        bfh[i] = *(const f16x8*)(&Bh[bw]);
        bfl[i] = *(const f16x8*)(&Bl[bw]);
      }
#pragma unroll
      for (int i = 0; i < 4; i++)
#pragma unroll
        for (int j = 0; j < 4; j++) {
          acc[i][j] = mfma_h(afh[i], bfh[j], acc[i][j]);
          acc[i][j] = mfma_h(afh[i], bfl[j], acc[i][j]);
          acc[i][j] = mfma_h(afl[i], bfh[j], acc[i][j]);
        }
    }
  }
#pragma unroll
  for (int i = 0; i < 4; i++)
#pragma unroll
    for (int r = 0; r < 4; r++) {
      const size_t row = m0 + wr * 64 + i * 16 + lq * 4 + r;
#pragma unroll
      for (int j = 0; j < 4; j++) {
        const int col = n0 + wc * 64 + j * 16 + lm;
        float v = acc[i][j][r];
        if constexpr (EPI == 0) {
          C[row * N + col] = v;
        } else if constexpr (EPI == 1) {
          v += bias[col] + xres[row * N + col];
          C[row * N + col] = v;
        } else {
          // EPI 2: qkv split-store (block-uniform section: n0 is 128-aligned)
          if (n0 < 768) v *= QSCALE;  // Q pre-scale (fp32, exact math fold)
          const f16 hh = (f16)v;
          const f16 ll = (f16)(v - (float)hh);
          if (n0 < 1536) {
            Oh[row * 1536 + col] = hh;
            Ol[row * 1536 + col] = ll;
          } else {
            Ov[row * 768 + (col - 1536)] =
                (u32)f16bits(hh) | ((u32)f16bits(ll) << 16);
          }
        }
      }
    }
}

// -------------------------------------------------- f16-split flash attention
// round-6 form (best measured: 98.4 us, 0 bank conflicts). KVBLK=64,
// Q/K/V pre-split by the qkv GEMM epilogue; Q pre-scaled by 0.125*log2e ->
// softmax in exp2f. LDS 48 KB; grid 768 blocks = 3 blocks/CU (grid-capped).
__global__ __launch_bounds__(256) void attn_f16s(
    const f16* __restrict__ qkh, const f16* __restrict__ qkl,
    const u32* __restrict__ vI, float* __restrict__ o, int qb) {
  __shared__ f16 Kh[64 * 64];
  __shared__ f16 Kl[64 * 64];
  __shared__ f16 Vh[64 * 64];
  __shared__ f16 Vl[64 * 64];
  __shared__ f16 Ph[4 * 16 * 64];
  __shared__ f16 Pl[4 * 16 * 64];
  const int bz = blockIdx.z, h = blockIdx.y, qt = blockIdx.x;
  const int tid = threadIdx.x, wv = tid >> 6, lane = tid & 63;
  const int lm = lane & 15, lq = lane >> 4;

  // Q fragments (A-layout): rows wv*16+lm, k = frag*32 + lq*8 .. +8
  f16x8 qh[2], ql[2];
  {
    const size_t qrow =
        (size_t)(bz * 1024 + qt * 64 + wv * 16 + lm) * 1536 + h * 64;
#pragma unroll
    for (int f = 0; f < 2; f++) {
      qh[f] = *(const f16x8*)(qkh + qrow + f * 32 + lq * 8);
      ql[f] = *(const f16x8*)(qkl + qrow + f * 32 + lq * 8);
    }
  }
  const f32x4 z4 = {0.f, 0.f, 0.f, 0.f};
  f32x4 oacc[4];
#pragma unroll
  for (int jb = 0; jb < 4; jb++) oacc[jb] = z4;
  float mrun[4], lrun[4];
#pragma unroll
  for (int r = 0; r < 4; r++) {
    mrun[r] = -1e30f;
    lrun[r] = 0.f;
  }
  const int vd = tid & 63;
  const int vkg = tid >> 6;
  f16* pwh = &Ph[wv * 16 * 64];
  f16* pwl = &Pl[wv * 16 * 64];

  for (int kt = 0; kt < 16; kt++) {
    __syncthreads();
    // stage K tile (64 keys x 64 dims) hi/lo from planes, swizzled
#pragma unroll
    for (int i = 0; i < 2; i++) {
      const int s2 = tid + i * 256;
      const int r = s2 >> 3, g = s2 & 7;
      const size_t kb =
          (size_t)(bz * 1024 + kt * 64 + r) * 1536 + 768 + h * 64 + g * 8;
      const int sw = r * 64 + ((g ^ (r & 7)) << 3);
      *(f16x8*)(&Kh[sw]) = *(const f16x8*)(qkh + kb);
      *(f16x8*)(&Kl[sw]) = *(const f16x8*)(qkl + kb);
    }
    // stage V transposed: Vt[dim][key] — u32 interleaved loads, bit-unpack
#pragma unroll
    for (int sseg = 0; sseg < 2; sseg++) {
      const int k0v = vkg * 16 + sseg * 8;
      f16x8 hh, ll;
#pragma unroll
      for (int j = 0; j < 8; j++) {
        const u32 w = vI[(size_t)(bz * 1024 + kt * 64 + k0v + j) * 768 +
                         h * 64 + vd];
        ((u16*)&hh)[j] = (u16)(w & 0xffffu);
        ((u16*)&ll)[j] = (u16)(w >> 16);
      }
      const int g = k0v >> 3;
      const int sw = vd * 64 + ((g ^ (vd & 7)) << 3);
      *(f16x8*)(&Vh[sw]) = hh;
      *(f16x8*)(&Vl[sw]) = ll;
    }
    __syncthreads();

    // S' = Q' K^T (pre-scaled; 16 q-rows x 64 keys), f16-split
    f32x4 sa[4];
#pragma unroll
    for (int j = 0; j < 4; j++) sa[j] = z4;
#pragma unroll
    for (int kx = 0; kx < 8; kx += 4) {
      const f16x8 ah = qh[kx >> 2], al = ql[kx >> 2];
#pragma unroll
      for (int j = 0; j < 4; j++) {
        const int rb = j * 16 + lm;
        const int bw = rb * 64 + (((rb & 7) ^ (kx + lq)) << 3);
        const f16x8 bh = *(const f16x8*)(&Kh[bw]);
        const f16x8 bl = *(const f16x8*)(&Kl[bw]);
        sa[j] = mfma_h(ah, bh, sa[j]);
        sa[j] = mfma_h(ah, bl, sa[j]);
        sa[j] = mfma_h(al, bh, sa[j]);
      }
    }

    // online softmax per q-row in base-2 (scale folded into Q)
#pragma unroll
    for (int r = 0; r < 4; r++) {
      float mx = fmaxf(fmaxf(sa[0][r], sa[1][r]), fmaxf(sa[2][r], sa[3][r]));
      mx = fmaxf(mx, __shfl_xor(mx, 1));
      mx = fmaxf(mx, __shfl_xor(mx, 2));
      mx = fmaxf(mx, __shfl_xor(mx, 4));
      mx = fmaxf(mx, __shfl_xor(mx, 8));
      const float mnew = fmaxf(mrun[r], mx);
      const float alpha = exp2f(mrun[r] - mnew);
      float ps = 0.f;
#pragma unroll
      for (int j = 0; j < 4; j++) {
        const float p = exp2f(sa[j][r] - mnew);
        sa[j][r] = p;
        ps += p;
      }
      ps += __shfl_xor(ps, 1);
      ps += __shfl_xor(ps, 2);
      ps += __shfl_xor(ps, 4);
      ps += __shfl_xor(ps, 8);
      lrun[r] = lrun[r] * alpha + ps;
      mrun[r] = mnew;
#pragma unroll
      for (int jb = 0; jb < 4; jb++) oacc[jb][r] *= alpha;
    }

    // P: C-layout -> per-wave LDS (A-layout roundtrip), split hi/lo
#pragma unroll
    for (int j = 0; j < 4; j++)
#pragma unroll
      for (int r = 0; r < 4; r++) {
        const int qr = lq * 4 + r;
        const int key = j * 16 + lm;
        const int ad = qr * 64 + (((qr & 7) ^ (key >> 3)) << 3) + (key & 7);
        const float p = sa[j][r];
        const f16 ph = (f16)p;
        pwh[ad] = ph;
        pwl[ad] = (f16)(p - (float)ph);
      }
    // O += P V, f16-split
#pragma unroll
    for (int kx2 = 0; kx2 < 8; kx2 += 4) {
      const int pw = lm * 64 + (((lm & 7) ^ (kx2 + lq)) << 3);
      const f16x8 pah = *(const f16x8*)(&pwh[pw]);
      const f16x8 pal = *(const f16x8*)(&pwl[pw]);
#pragma unroll
      for (int jb = 0; jb < 4; jb++) {
        const int rb = jb * 16 + lm;
        const int vw = rb * 64 + (((rb & 7) ^ (kx2 + lq)) << 3);
        const f16x8 vh = *(const f16x8*)(&Vh[vw]);
        const f16x8 vl = *(const f16x8*)(&Vl[vw]);
        oacc[jb] = mfma_h(pah, vh, oacc[jb]);
        oacc[jb] = mfma_h(pah, vl, oacc[jb]);
        oacc[jb] = mfma_h(pal, vh, oacc[jb]);
      }
    }
  }
  const int gtok = (qb * 4 + bz) * 1024 + qt * 64;
#pragma unroll
  for (int r = 0; r < 4; r++) {
    const float inv = 1.f / lrun[r];
    const size_t row = (size_t)gtok + wv * 16 + lq * 4 + r;
#pragma unroll
    for (int jb = 0; jb < 4; jb++) {
      const int col = h * 64 + jb * 16 + lm;
      o[row * CDIM + col] = oacc[jb][r] * inv;
    }
  }
}

// -------------------------------------------------- bf16 expert GEMM
// v3: no atomics. 1-D grid (6144 blocks), did&7 = expert = XCD (round-robin
// dispatch) so each XCD's L2 holds exactly one expert's B panel + its A rows.
// Output: weighted f16 rows plain-stored into compact C_perm[32768][768]
// (lives in d_out), row = eBase[e] + rowi. 2-phase reg prefetch kept.
__global__ __launch_bounds__(256) void gemm_expert(
    const u16* __restrict__ A, const u16* __restrict__ Bt,
    __half* __restrict__ Cp, int N, int K, const float* __restrict__ bias,
    const int* __restrict__ counts, const int* __restrict__ eBase,
    const int* __restrict__ tokList, const float* __restrict__ wgtList) {
  __shared__ u16 As[128 * 64];
  __shared__ u16 Bs[128 * 64];
  const int did = blockIdx.x;
  const int e = did & 7;        // expert pinned to XCD
  const int s = did >> 3;       // 0..767 within expert
  const int bx = s % 6;         // n-block
  const int by = s / 6;         // m-panel (real work front-loaded per XCD)
  const int cnt = counts[e];
  const int m0 = by * 128, n0 = bx * 128;
  if (m0 >= cnt) return;
  const int tid = threadIdx.x;
  const int lane = tid & 63, wv = tid >> 6;
  const int wr = wv >> 1, wc = wv & 1;
  const int lm = lane & 15, lq = lane >> 4;
  const u16* Bte = Bt + (size_t)e * N * K;
  const int* tokl = tokList + e * TOKENS;
  const float* wl = wgtList + e * TOKENS;
  const float* biasE = bias + e * N;
  const int base0 = eBase[e];

  // hoisted staging geometry: thread stages A/B rows r0 + {0,32,64,96}
  const int r0 = tid >> 3, g = tid & 7;
  const int swz = (g ^ (r0 & 7)) << 3;  // (r0+i*32)&7 == r0&7
  const u16* ap[4];
  const u16* bp[4];
#pragma unroll
  for (int i = 0; i < 4; i++) {
    const int row = m0 + r0 + i * 32;
    const int tok = (row < cnt) ? tokl[row] : 0;
    ap[i] = A + (size_t)tok * K + g * 8;
    bp[i] = Bte + (size_t)(n0 + r0 + i * 32) * K + g * 8;
  }

  f32x4 acc[4][4];
  const f32x4 z4 = {0.f, 0.f, 0.f, 0.f};
#pragma unroll
  for (int i = 0; i < 4; i++)
#pragma unroll
    for (int j = 0; j < 4; j++) acc[i][j] = z4;

  // prologue: tile 0 -> regs -> LDS
  u32x4 pa[4], pb[4];
#pragma unroll
  for (int i = 0; i < 4; i++) {
    pa[i] = *(const u32x4*)(ap[i]);
    pb[i] = *(const u32x4*)(bp[i]);
  }
#pragma unroll
  for (int i = 0; i < 4; i++) {
    *(u32x4*)(&As[(r0 + i * 32) * 64 + swz]) = pa[i];
    *(u32x4*)(&Bs[(r0 + i * 32) * 64 + swz]) = pb[i];
  }

  for (int k0 = 0; k0 < K; k0 += 64) {
    __syncthreads();  // LDS tile k0 ready
    const bool more = (k0 + 64) < K;
    if (more) {
#pragma unroll
      for (int i = 0; i < 4; i++) {
        pa[i] = *(const u32x4*)(ap[i] + k0 + 64);
        pb[i] = *(const u32x4*)(bp[i] + k0 + 64);
      }
    }
#pragma unroll
    for (int kx = 0; kx < 8; kx += 4) {
      bf16x8 af[4], bfv[4];
#pragma unroll
      for (int i = 0; i < 4; i++) {
        const int ra = wr * 64 + i * 16 + lm;
        af[i] = *(const bf16x8*)(&As[ra * 64 + (((ra & 7) ^ (kx + lq)) << 3)]);
        const int rb = wc * 64 + i * 16 + lm;
        bfv[i] = *(const bf16x8*)(&Bs[rb * 64 + (((rb & 7) ^ (kx + lq)) << 3)]);
      }
#pragma unroll
      for (int i = 0; i < 4; i++)
#pragma unroll
        for (int j = 0; j < 4; j++)
          acc[i][j] = mfma_bf(af[i], bfv[j], acc[i][j]);
    }
    __syncthreads();  // all waves done reading LDS tile k0
    if (more) {
#pragma unroll
      for (int i = 0; i < 4; i++) {
        *(u32x4*)(&As[(r0 + i * 32) * 64 + swz]) = pa[i];
        *(u32x4*)(&Bs[(r0 + i * 32) * 64 + swz]) = pb[i];
      }
    }
  }
#pragma unroll
  for (int i = 0; i < 4; i++)
#pragma unroll
    for (int r = 0; r < 4; r++) {
      const int rowi = m0 + wr * 64 + i * 16 + lq * 4 + r;
      const bool live = (rowi < cnt);
      const float w = live ? wl[rowi] : 0.f;
      const size_t prow = live ? (size_t)(base0 + rowi) * (size_t)N : 0;
#pragma unroll
      for (int j = 0; j < 4; j++) {
        const int col = n0 + wc * 64 + j * 16 + lm;
        const float v = (acc[i][j][r] + biasE[col]) * w;
        // pair lanes: even lm stores (col, col+1) as one __half2
        const float vn = __shfl_xor(v, 1);
        if (live && (lm & 1) == 0) {
          *(__half2*)(Cp + prow + col) =
              __halves2half2(__float2half(v), __float2half(vn));
        }
      }
    }
}

// -------------------------------------------------- router (all fp32)
__global__ __launch_bounds__(256) void router_kernel(
    const float* __restrict__ x2, const float* __restrict__ g2,
    const float* __restrict__ b2, const float* __restrict__ rw,
    const float* __restrict__ rb, const float* __restrict__ rlng,
    const float* __restrict__ rlnb, const float* __restrict__ noise,
    int* __restrict__ eidx, float* __restrict__ ewgt) {
  const int token = blockIdx.x * 4 + (threadIdx.x >> 6);
  const int lane = threadIdx.x & 63;
  const size_t base = (size_t)token * CDIM;
  float v[12];
  float s = 0.f, ss = 0.f;
#pragma unroll
  for (int j = 0; j < 12; j++) {
    const int idx = lane + j * 64;
    v[j] = x2[base + idx];
    s += v[j];
    ss += v[j] * v[j];
  }
#pragma unroll
  for (int m = 1; m < 64; m <<= 1) {
    s += __shfl_xor(s, m);
    ss += __shfl_xor(ss, m);
  }
  const float mean = s * (1.f / CDIM);
  const float var = ss * (1.f / CDIM) - mean * mean;
  const float rs = rsqrtf(var + 1e-5f);

  float acc[8];
#pragma unroll
  for (int e = 0; e < 8; e++) acc[e] = 0.f;
#pragma unroll
  for (int j = 0; j < 12; j++) {
    const int d = lane + j * 64;
    const float hv = (v[j] - mean) * rs * g2[d] + b2[d];
    const f32x4 w0v = *(const f32x4*)(rw + (size_t)d * 8);
    const f32x4 w1v = *(const f32x4*)(rw + (size_t)d * 8 + 4);
#pragma unroll
    for (int e = 0; e < 4; e++) {
      acc[e] += hv * w0v[e];
      acc[e + 4] += hv * w1v[e];
    }
  }
#pragma unroll
  for (int m = 1; m < 64; m <<= 1)
#pragma unroll
    for (int e = 0; e < 8; e++) acc[e] += __shfl_xor(acc[e], m);

  float y[8];
  float emean = 0.f;
#pragma unroll
  for (int e = 0; e < 8; e++) {
    y[e] = acc[e] + rb[e];
    emean += y[e];
  }
  emean *= 0.125f;
  float evar = 0.f;
#pragma unroll
  for (int e = 0; e < 8; e++) {
    const float d = y[e] - emean;
    evar += d * d;
  }
  evar *= 0.125f;
  const float ers = rsqrtf(evar + 1e-5f);
  float lg[8];
  float mx = -1e30f;
#pragma unroll
  for (int e = 0; e < 8; e++) {
    lg[e] = (y[e] - emean) * ers * rlng[e] + rlnb[e];
    mx = fmaxf(mx, lg[e]);
  }
  float se = 0.f;
#pragma unroll
  for (int e = 0; e < 8; e++) {
    lg[e] = expf(lg[e] - mx);
    se += lg[e];
  }
  const float inv = 1.f / se;
  float r2[8];
#pragma unroll
  for (int e = 0; e < 8; e++)
    r2[e] = lg[e] * inv + noise[(size_t)token * 8 + e] * 0.125f;

  int e0 = 0;
  float v0 = r2[0];
#pragma unroll
  for (int e = 1; e < 8; e++)
    if (r2[e] > v0) {
      v0 = r2[e];
      e0 = e;
    }
  int e1 = -1;
  float v1 = -1e30f;
#pragma unroll
  for (int e = 0; e < 8; e++)
    if (e != e0 && r2[e] > v1) {
      v1 = r2[e];
      e1 = e;
    }
  const float w0 = 1.f / (1.f + expf(v1 - v0));
  if (lane == 0) {
    eidx[token * 2] = e0;
    eidx[token * 2 + 1] = e1;
    ewgt[token * 2] = w0;
    ewgt[token * 2 + 1] = 1.f - w0;
  }
}

// -------------------------------------------------- lists (+ inverse pos map)
__global__ __launch_bounds__(256) void build_lists(
    const int* __restrict__ eidx, const float* __restrict__ ewgt,
    int* __restrict__ counts, int* __restrict__ tokL, float* __restrict__ wgtL,
    int* __restrict__ posL) {
  const int e = blockIdx.x;
  __shared__ int cnt;
  if (threadIdx.x == 0) cnt = 0;
  __syncthreads();
  const int lane = threadIdx.x & 63;
  for (int t = threadIdx.x; t < TOKENS; t += 256) {
#pragma unroll
    for (int k = 0; k < 2; k++) {
      const bool match = (eidx[t * 2 + k] == e);
      const unsigned long long mb = __ballot(match);
      if (mb) {
        const int leader = __ffsll((unsigned long long)mb) - 1;
        int base = 0;
        if (lane == leader) base = atomicAdd(&cnt, __popcll(mb));
        base = __shfl(base, leader);
        if (match) {
          const int rank = __popcll(mb & ((1ull << lane) - 1ull));
          tokL[e * TOKENS + base + rank] = t;
          wgtL[e * TOKENS + base + rank] = ewgt[t * 2 + k];
          posL[t * 2 + k] = base + rank;
        }
      }
    }
  }
  __syncthreads();
  if (threadIdx.x == 0) counts[e] = cnt;
}

// -------------------------------------------------- prefix over 8 counts
__global__ void prefix_counts(const int* __restrict__ counts,
                              int* __restrict__ eBase) {
  if (threadIdx.x == 0) {
    int s = 0;
#pragma unroll
    for (int e = 0; e < NEXP; e++) {
      eBase[e] = s;
      s += counts[e];
    }
    eBase[NEXP] = s;
  }
}

// -------------------------------------------------- combine: x2 += moe rows
__global__ __launch_bounds__(256) void combine_moe(
    float* __restrict__ x2, const __half* __restrict__ Cp,
    const int* __restrict__ eidx, const int* __restrict__ posL,
    const int* __restrict__ eBase) {
  const int t = blockIdx.x * 4 + (threadIdx.x >> 6);
  const int lane = threadIdx.x & 63;
  const int e0 = eidx[t * 2], e1 = eidx[t * 2 + 1];
  const size_t q0 = (size_t)(eBase[e0] + posL[t * 2]) * CDIM;
  const size_t q1 = (size_t)(eBase[e1] + posL[t * 2 + 1]) * CDIM;
  const size_t base = (size_t)t * CDIM;
#pragma unroll
  for (int j = 0; j < 12; j++) {
    const int d = lane + j * 64;
    const float m =
        __half2float(Cp[q0 + d]) + __half2float(Cp[q1 + d]);
    x2[base + d] += m;
  }
}

// -------------------------------------------------- copy
__global__ __launch_bounds__(256) void copy_f32(const float* __restrict__ in,
                                                float* __restrict__ out) {
  const int i = (blockIdx.x * 256 + threadIdx.x) * 4;
  *(float4*)(out + i) = *(const float4*)(in + i);
}

// -------------------------------------------------- launch
extern "C" void kernel_launch(void* const* d_in, const int* in_sizes, int n_in,
                              void* d_out, int out_size, void* d_ws,
                              size_t ws_size, hipStream_t stream) {
  const float* x = (const float*)d_in[0];
  const float* noise = (const float*)d_in[1];
  const float* ln1_g = (const float*)d_in[2];
  const float* ln1_b = (const float*)d_in[3];
  const float* qkv_w = (const float*)d_in[4];
  const float* proj_w = (const float*)d_in[5];
  const float* proj_b = (const float*)d_in[6];
  const float* ln2_g = (const float*)d_in[7];
  const float* ln2_b = (const float*)d_in[8];
  const float* route_w = (const float*)d_in[9];
  const float* route_b = (const float*)d_in[10];
  const float* rln_g = (const float*)d_in[11];
  const float* rln_b = (const float*)d_in[12];
  const float* expert_w = (const float*)d_in[13];
  const float* expert_b = (const float*)d_in[14];

  char* ws = (char*)d_ws;
  // [0, 50331648)            x2f fp32 (residual + accumulation target)
  // [50331648, 88080384)     qkv split planes for the active quarter:
  //   qkh  [4096][1536] f16  @ +50331648  (12582912 B)  Q|K hi
  //   qkl  [4096][1536] f16  @ +62914560  (12582912 B)  Q|K lo
  //   vIq  [4096][768]  u32  @ +75497472  (12582912 B)  V hi|lo packed
  // post-attn this region is reused for exp_wt + h2 + lists
  float* x2f = (float*)(ws);
  f16* qkh = (f16*)(ws + 50331648);
  f16* qkl = (f16*)(ws + 62914560);
  u32* vIq = (u32*)(ws + 75497472);
  u16* exp_wt = (u16*)(ws + 50331648);    // 9437184 (post-attn)
  u16* h2 = (u16*)(ws + 59768832);        // 25165824 (post-attn)
  int* counts = (int*)(ws + 84934656);    // 64
  int* eBase = (int*)(ws + 84934784);     // 64 (within counts' 256-B slot)
  int* eidx = (int*)(ws + 84934912);      // 131072
  float* ewgt = (float*)(ws + 85065984);  // 131072
  int* tokL = (int*)(ws + 85197056);      // 524288
  float* wgtL = (float*)(ws + 85721344);  // 524288
  int* posL = (int*)(ws + 86245632);      // 131072 -> end 86376704
  // weight f16 planes (persist until proj gemm; disjoint from qkv region)
  f16* qkvw_h = (f16*)(ws + 88080384);    // 3538944
  f16* qkvw_l = (f16*)(ws + 91619328);    // 3538944
  f16* projw_h = (f16*)(ws + 95158272);   // 1179648
  f16* projw_l = (f16*)(ws + 96337920);   // 1179648  -> end 97517568
  // h1f (post-LN1) and attention output ping-pong through d_out (fp32).
  // Post-proj, d_out is reused as C_perm: 32768 x 768 f16 = out_size exactly.
  float* h1f = (float*)d_out;
  __half* cperm = (__half*)d_out;

  const dim3 blk(256);
  transpose_split_f16<<<dim3(36, 12), blk, 0, stream>>>(qkv_w, qkvw_h, qkvw_l,
                                                        768, 2304);
  transpose_split_f16<<<dim3(12, 12), blk, 0, stream>>>(proj_w, projw_h,
                                                        projw_l, 768, 768);
  ln_rows<false><<<dim3(4096), blk, 0, stream>>>(x, ln1_g, ln1_b, h1f);
  for (int q = 0; q < 4; q++) {
    gemm_f16s<2><<<dim3(18, 32), blk, 0, stream>>>(
        h1f + (size_t)q * 4096 * 768, qkvw_h, qkvw_l, nullptr, 4096, 2304,
        768, nullptr, nullptr, qkh, qkl, vIq);
    attn_f16s<<<dim3(16, 12, 4), blk, 0, stream>>>(qkh, qkl, vIq, h1f, q);
  }
  gemm_f16s<1><<<dim3(6, 128), blk, 0, stream>>>(h1f, projw_h, projw_l, x2f,
                                                 16384, 768, 768, proj_b, x,
                                                 nullptr, nullptr, nullptr);
  ln_rows<true><<<dim3(4096), blk, 0, stream>>>(x2f, ln2_g, ln2_b, h2);
  transpose_f32_bf16<<<dim3(12, 12, 8), blk, 0, stream>>>(expert_w, exp_wt,
                                                          768, 768);
  router_kernel<<<dim3(4096), blk, 0, stream>>>(x2f, ln2_g, ln2_b, route_w,
                                                route_b, rln_g, rln_b, noise,
                                                eidx, ewgt);
  build_lists<<<dim3(8), blk, 0, stream>>>(eidx, ewgt, counts, tokL, wgtL,
                                           posL);
  prefix_counts<<<dim3(1), dim3(64), 0, stream>>>(counts, eBase);
  gemm_expert<<<dim3(6144), blk, 0, stream>>>(h2, exp_wt, cperm, 768, 768,
                                              expert_b, counts, eBase, tokL,
                                              wgtL);
  combine_moe<<<dim3(4096), blk, 0, stream>>>(x2f, cperm, eidx, posL, eBase);
  copy_f32<<<dim3(12288), blk, 0, stream>>>(x2f, (float*)d_out);
}

// Round 11
// 1087.231 us; speedup vs baseline: 1.0925x; 1.0363x over previous
//
#include <hip/hip_runtime.h>
#include <hip/hip_fp16.h>

typedef unsigned short u16;
typedef unsigned int u32;
typedef _Float16 f16;
typedef short bf16x8 __attribute__((ext_vector_type(8)));
typedef f16 f16x8 __attribute__((ext_vector_type(8)));
typedef float f32x4 __attribute__((ext_vector_type(4)));
typedef u32 u32x4 __attribute__((ext_vector_type(4)));

#define TOKENS 16384   // B*N = 16*1024
#define CDIM 768
#define NEXP 8

// 0.125 (Dh^-0.5) * log2(e): folded into the Q plane so softmax runs in exp2
#define QSCALE 0.18033688011112043f

__device__ __forceinline__ u16 f2b(float f) {
  u32 u = __float_as_uint(f);
  return (u16)((u + 0x7fffu + ((u >> 16) & 1u)) >> 16);
}
__device__ __forceinline__ u16 f16bits(f16 x) {
  union { f16 f; u16 u; } c;
  c.f = x;
  return c.u;
}
__device__ __forceinline__ f32x4 mfma_bf(bf16x8 a, bf16x8 b, f32x4 c) {
  return __builtin_amdgcn_mfma_f32_16x16x32_bf16(a, b, c, 0, 0, 0);
}
__device__ __forceinline__ f32x4 mfma_h(f16x8 a, f16x8 b, f32x4 c) {
  return __builtin_amdgcn_mfma_f32_16x16x32_f16(a, b, c, 0, 0, 0);
}
// split 8 fp32 into f16 hi/lo planes (x = hi + lo, err ~2^-22|x|)
__device__ __forceinline__ void split8(const float* v, f16x8& h, f16x8& l) {
#pragma unroll
  for (int i = 0; i < 8; i++) {
    const f16 hh = (f16)v[i];
    h[i] = hh;
    l[i] = (f16)(v[i] - (float)hh);
  }
}

// -------------------------------------------------- transpose+split (f16)
// in: K x N fp32 -> oh/ol: N x K f16 hi/lo planes
__global__ __launch_bounds__(256) void transpose_split_f16(
    const float* __restrict__ in, f16* __restrict__ oh, f16* __restrict__ ol,
    int K, int N) {
  __shared__ float tile[64][65];
  const int n0 = blockIdx.x * 64, k0 = blockIdx.y * 64;
#pragma unroll
  for (int i = 0; i < 16; i++) {
    const int s = threadIdx.x + i * 256;
    const int r = s >> 6, c = s & 63;
    tile[r][c] = in[(size_t)(k0 + r) * N + n0 + c];
  }
  __syncthreads();
#pragma unroll
  for (int i = 0; i < 16; i++) {
    const int s = threadIdx.x + i * 256;
    const int r = s >> 6, c = s & 63;
    const float v = tile[c][r];
    const f16 h = (f16)v;
    oh[(size_t)(n0 + r) * K + k0 + c] = h;
    ol[(size_t)(n0 + r) * K + k0 + c] = (f16)(v - (float)h);
  }
}

// -------------------------------------------------- transpose (bf16, experts)
__global__ __launch_bounds__(256) void transpose_f32_bf16(
    const float* __restrict__ in, u16* __restrict__ out, int K, int N) {
  __shared__ u16 tile[64][65];
  const int z = blockIdx.z;
  in += (size_t)z * K * N;
  out += (size_t)z * K * N;
  const int n0 = blockIdx.x * 64, k0 = blockIdx.y * 64;
#pragma unroll
  for (int i = 0; i < 16; i++) {
    const int s = threadIdx.x + i * 256;
    const int r = s >> 6, c = s & 63;
    tile[r][c] = f2b(in[(size_t)(k0 + r) * N + n0 + c]);
  }
  __syncthreads();
#pragma unroll
  for (int i = 0; i < 16; i++) {
    const int s = threadIdx.x + i * 256;
    const int r = s >> 6, c = s & 63;
    out[(size_t)(n0 + r) * K + k0 + c] = tile[c][r];
  }
}

// -------------------------------------------------- layernorm
template <bool BF16OUT>
__global__ __launch_bounds__(256) void ln_rows(const float* __restrict__ in,
                                               const float* __restrict__ g,
                                               const float* __restrict__ bt,
                                               void* __restrict__ out) {
  const int row = blockIdx.x * 4 + (threadIdx.x >> 6);
  const int lane = threadIdx.x & 63;
  const size_t base = (size_t)row * CDIM;
  float v[12];
  float s = 0.f, ss = 0.f;
#pragma unroll
  for (int j = 0; j < 12; j++) {
    const int idx = lane + j * 64;
    v[j] = in[base + idx];
    s += v[j];
    ss += v[j] * v[j];
  }
#pragma unroll
  for (int m = 1; m < 64; m <<= 1) {
    s += __shfl_xor(s, m);
    ss += __shfl_xor(ss, m);
  }
  const float mean = s * (1.f / CDIM);
  const float var = ss * (1.f / CDIM) - mean * mean;
  const float rs = rsqrtf(var + 1e-5f);
#pragma unroll
  for (int j = 0; j < 12; j++) {
    const int idx = lane + j * 64;
    const float y = (v[j] - mean) * rs * g[idx] + bt[idx];
    if (BF16OUT)
      ((u16*)out)[base + idx] = f2b(y);
    else
      ((float*)out)[base + idx] = y;
  }
}

// -------------------------------------------------- f16-split GEMM
// round-6 form (best measured). C[M,N] = A[M,K](fp32, split in-kernel) *
// Bt[N,K](pre-split f16 hi/lo). 128x128 tile, BK=64, 4 waves 2x2, 16x16x32
// f16 MFMA, 3 MFMAs per product (hh + hl + lh) -> ~2^-21 relative.
// XOR-swizzled LDS (16B granules). BK=32 variant regressed (r10: +37us —
// doubled per-K-step barrier/drain costs beat the occupancy gain).
// EPI 0: plain fp32 store. EPI 1: C = acc + bias[col] + xres[row,col].
// EPI 2 (qkv): store pre-split f16 planes — Q cols (n0<768, scaled by QSCALE)
//   and K cols (768<=n0<1536) planar into Oh/Ol[row*1536+col]; V cols
//   (n0>=1536) packed (hi | lo<<16) into Ov[row*768+col-1536].
template <int EPI>
__global__ __launch_bounds__(256) void gemm_f16s(
    const float* __restrict__ A, const f16* __restrict__ Bth,
    const f16* __restrict__ Btl, float* __restrict__ C, int M, int N, int K,
    const float* __restrict__ bias, const float* __restrict__ xres,
    f16* __restrict__ Oh, f16* __restrict__ Ol, u32* __restrict__ Ov) {
  __shared__ f16 Ah[128 * 64];
  __shared__ f16 Al[128 * 64];
  __shared__ f16 Bh[128 * 64];
  __shared__ f16 Bl[128 * 64];
  const int tid = threadIdx.x;
  const int lane = tid & 63, wv = tid >> 6;
  const int wr = wv >> 1, wc = wv & 1;
  const int lm = lane & 15, lq = lane >> 4;
  const int m0 = blockIdx.y * 128, n0 = blockIdx.x * 128;
  f32x4 acc[4][4];
  const f32x4 z4 = {0.f, 0.f, 0.f, 0.f};
#pragma unroll
  for (int i = 0; i < 4; i++)
#pragma unroll
    for (int j = 0; j < 4; j++) acc[i][j] = z4;

  for (int k0 = 0; k0 < K; k0 += 64) {
    __syncthreads();
#pragma unroll
    for (int i = 0; i < 4; i++) {
      const int s = tid + i * 256;
      const int r = s >> 3, g = s & 7;
      float av[8];
      *(float4*)&av[0] = *(const float4*)(A + (size_t)(m0 + r) * K + k0 + g * 8);
      *(float4*)&av[4] =
          *(const float4*)(A + (size_t)(m0 + r) * K + k0 + g * 8 + 4);
      f16x8 hh, ll;
      split8(av, hh, ll);
      const int sw = r * 64 + ((g ^ (r & 7)) << 3);
      *(f16x8*)(&Ah[sw]) = hh;
      *(f16x8*)(&Al[sw]) = ll;
      *(f16x8*)(&Bh[sw]) = *(const f16x8*)(Bth + (size_t)(n0 + r) * K + k0 + g * 8);
      *(f16x8*)(&Bl[sw]) = *(const f16x8*)(Btl + (size_t)(n0 + r) * K + k0 + g * 8);
    }
    __syncthreads();
#pragma unroll
    for (int kx = 0; kx < 8; kx += 4) {
      f16x8 afh[4], afl[4], bfh[4], bfl[4];
#pragma unroll
      for (int i = 0; i < 4; i++) {
        const int ra = wr * 64 + i * 16 + lm;
        const int aw = ra * 64 + (((ra & 7) ^ (kx + lq)) << 3);
        afh[i] = *(const f16x8*)(&Ah[aw]);
        afl[i] = *(const f16x8*)(&Al[aw]);
        const int rb = wc * 64 + i * 16 + lm;
        const int bw = rb * 64 + (((rb & 7) ^ (kx + lq)) << 3);
        bfh[i] = *(const f16x8*)(&Bh[bw]);
        bfl[i] = *(const f16x8*)(&Bl[bw]);
      }
#pragma unroll
      for (int i = 0; i < 4; i++)
#pragma unroll
        for (int j = 0; j < 4; j++) {
          acc[i][j] = mfma_h(afh[i], bfh[j], acc[i][j]);
          acc[i][j] = mfma_h(afh[i], bfl[j], acc[i][j]);
          acc[i][j] = mfma_h(afl[i], bfh[j], acc[i][j]);
        }
    }
  }
#pragma unroll
  for (int i = 0; i < 4; i++)
#pragma unroll
    for (int r = 0; r < 4; r++) {
      const size_t row = m0 + wr * 64 + i * 16 + lq * 4 + r;
#pragma unroll
      for (int j = 0; j < 4; j++) {
        const int col = n0 + wc * 64 + j * 16 + lm;
        float v = acc[i][j][r];
        if constexpr (EPI == 0) {
          C[row * N + col] = v;
        } else if constexpr (EPI == 1) {
          v += bias[col] + xres[row * N + col];
          C[row * N + col] = v;
        } else {
          // EPI 2: qkv split-store (block-uniform section: n0 is 128-aligned)
          if (n0 < 768) v *= QSCALE;  // Q pre-scale (fp32, exact math fold)
          const f16 hh = (f16)v;
          const f16 ll = (f16)(v - (float)hh);
          if (n0 < 1536) {
            Oh[row * 1536 + col] = hh;
            Ol[row * 1536 + col] = ll;
          } else {
            Ov[row * 768 + (col - 1536)] =
                (u32)f16bits(hh) | ((u32)f16bits(ll) << 16);
          }
        }
      }
    }
}

// -------------------------------------------------- f16-split flash attention
// round-6 form (best measured: 97.7 us, 0 bank conflicts). KVBLK=64,
// Q/K/V pre-split by the qkv GEMM epilogue; Q pre-scaled by 0.125*log2e ->
// softmax in exp2f. LDS 48 KB; grid 768 blocks = 3 blocks/CU (grid-capped).
__global__ __launch_bounds__(256) void attn_f16s(
    const f16* __restrict__ qkh, const f16* __restrict__ qkl,
    const u32* __restrict__ vI, float* __restrict__ o, int qb) {
  __shared__ f16 Kh[64 * 64];
  __shared__ f16 Kl[64 * 64];
  __shared__ f16 Vh[64 * 64];
  __shared__ f16 Vl[64 * 64];
  __shared__ f16 Ph[4 * 16 * 64];
  __shared__ f16 Pl[4 * 16 * 64];
  const int bz = blockIdx.z, h = blockIdx.y, qt = blockIdx.x;
  const int tid = threadIdx.x, wv = tid >> 6, lane = tid & 63;
  const int lm = lane & 15, lq = lane >> 4;

  // Q fragments (A-layout): rows wv*16+lm, k = frag*32 + lq*8 .. +8
  f16x8 qh[2], ql[2];
  {
    const size_t qrow =
        (size_t)(bz * 1024 + qt * 64 + wv * 16 + lm) * 1536 + h * 64;
#pragma unroll
    for (int f = 0; f < 2; f++) {
      qh[f] = *(const f16x8*)(qkh + qrow + f * 32 + lq * 8);
      ql[f] = *(const f16x8*)(qkl + qrow + f * 32 + lq * 8);
    }
  }
  const f32x4 z4 = {0.f, 0.f, 0.f, 0.f};
  f32x4 oacc[4];
#pragma unroll
  for (int jb = 0; jb < 4; jb++) oacc[jb] = z4;
  float mrun[4], lrun[4];
#pragma unroll
  for (int r = 0; r < 4; r++) {
    mrun[r] = -1e30f;
    lrun[r] = 0.f;
  }
  const int vd = tid & 63;
  const int vkg = tid >> 6;
  f16* pwh = &Ph[wv * 16 * 64];
  f16* pwl = &Pl[wv * 16 * 64];

  for (int kt = 0; kt < 16; kt++) {
    __syncthreads();
    // stage K tile (64 keys x 64 dims) hi/lo from planes, swizzled
#pragma unroll
    for (int i = 0; i < 2; i++) {
      const int s2 = tid + i * 256;
      const int r = s2 >> 3, g = s2 & 7;
      const size_t kb =
          (size_t)(bz * 1024 + kt * 64 + r) * 1536 + 768 + h * 64 + g * 8;
      const int sw = r * 64 + ((g ^ (r & 7)) << 3);
      *(f16x8*)(&Kh[sw]) = *(const f16x8*)(qkh + kb);
      *(f16x8*)(&Kl[sw]) = *(const f16x8*)(qkl + kb);
    }
    // stage V transposed: Vt[dim][key] — u32 interleaved loads, bit-unpack
#pragma unroll
    for (int sseg = 0; sseg < 2; sseg++) {
      const int k0v = vkg * 16 + sseg * 8;
      f16x8 hh, ll;
#pragma unroll
      for (int j = 0; j < 8; j++) {
        const u32 w = vI[(size_t)(bz * 1024 + kt * 64 + k0v + j) * 768 +
                         h * 64 + vd];
        ((u16*)&hh)[j] = (u16)(w & 0xffffu);
        ((u16*)&ll)[j] = (u16)(w >> 16);
      }
      const int g = k0v >> 3;
      const int sw = vd * 64 + ((g ^ (vd & 7)) << 3);
      *(f16x8*)(&Vh[sw]) = hh;
      *(f16x8*)(&Vl[sw]) = ll;
    }
    __syncthreads();

    // S' = Q' K^T (pre-scaled; 16 q-rows x 64 keys), f16-split
    f32x4 sa[4];
#pragma unroll
    for (int j = 0; j < 4; j++) sa[j] = z4;
#pragma unroll
    for (int kx = 0; kx < 8; kx += 4) {
      const f16x8 ah = qh[kx >> 2], al = ql[kx >> 2];
#pragma unroll
      for (int j = 0; j < 4; j++) {
        const int rb = j * 16 + lm;
        const int bw = rb * 64 + (((rb & 7) ^ (kx + lq)) << 3);
        const f16x8 bh = *(const f16x8*)(&Kh[bw]);
        const f16x8 bl = *(const f16x8*)(&Kl[bw]);
        sa[j] = mfma_h(ah, bh, sa[j]);
        sa[j] = mfma_h(ah, bl, sa[j]);
        sa[j] = mfma_h(al, bh, sa[j]);
      }
    }

    // online softmax per q-row in base-2 (scale folded into Q)
#pragma unroll
    for (int r = 0; r < 4; r++) {
      float mx = fmaxf(fmaxf(sa[0][r], sa[1][r]), fmaxf(sa[2][r], sa[3][r]));
      mx = fmaxf(mx, __shfl_xor(mx, 1));
      mx = fmaxf(mx, __shfl_xor(mx, 2));
      mx = fmaxf(mx, __shfl_xor(mx, 4));
      mx = fmaxf(mx, __shfl_xor(mx, 8));
      const float mnew = fmaxf(mrun[r], mx);
      const float alpha = exp2f(mrun[r] - mnew);
      float ps = 0.f;
#pragma unroll
      for (int j = 0; j < 4; j++) {
        const float p = exp2f(sa[j][r] - mnew);
        sa[j][r] = p;
        ps += p;
      }
      ps += __shfl_xor(ps, 1);
      ps += __shfl_xor(ps, 2);
      ps += __shfl_xor(ps, 4);
      ps += __shfl_xor(ps, 8);
      lrun[r] = lrun[r] * alpha + ps;
      mrun[r] = mnew;
#pragma unroll
      for (int jb = 0; jb < 4; jb++) oacc[jb][r] *= alpha;
    }

    // P: C-layout -> per-wave LDS (A-layout roundtrip), split hi/lo
#pragma unroll
    for (int j = 0; j < 4; j++)
#pragma unroll
      for (int r = 0; r < 4; r++) {
        const int qr = lq * 4 + r;
        const int key = j * 16 + lm;
        const int ad = qr * 64 + (((qr & 7) ^ (key >> 3)) << 3) + (key & 7);
        const float p = sa[j][r];
        const f16 ph = (f16)p;
        pwh[ad] = ph;
        pwl[ad] = (f16)(p - (float)ph);
      }
    // O += P V, f16-split
#pragma unroll
    for (int kx2 = 0; kx2 < 8; kx2 += 4) {
      const int pw = lm * 64 + (((lm & 7) ^ (kx2 + lq)) << 3);
      const f16x8 pah = *(const f16x8*)(&pwh[pw]);
      const f16x8 pal = *(const f16x8*)(&pwl[pw]);
#pragma unroll
      for (int jb = 0; jb < 4; jb++) {
        const int rb = jb * 16 + lm;
        const int vw = rb * 64 + (((rb & 7) ^ (kx2 + lq)) << 3);
        const f16x8 vh = *(const f16x8*)(&Vh[vw]);
        const f16x8 vl = *(const f16x8*)(&Vl[vw]);
        oacc[jb] = mfma_h(pah, vh, oacc[jb]);
        oacc[jb] = mfma_h(pah, vl, oacc[jb]);
        oacc[jb] = mfma_h(pal, vh, oacc[jb]);
      }
    }
  }
  const int gtok = (qb * 4 + bz) * 1024 + qt * 64;
#pragma unroll
  for (int r = 0; r < 4; r++) {
    const float inv = 1.f / lrun[r];
    const size_t row = (size_t)gtok + wv * 16 + lq * 4 + r;
#pragma unroll
    for (int jb = 0; jb < 4; jb++) {
      const int col = h * 64 + jb * 16 + lm;
      o[row * CDIM + col] = oacc[jb][r] * inv;
    }
  }
}

// -------------------------------------------------- bf16 expert GEMM
// v3: no atomics. 1-D grid (6144 blocks), did&7 = expert = XCD (round-robin
// dispatch) so each XCD's L2 holds exactly one expert's B panel + its A rows.
// Output: weighted f16 rows plain-stored into compact C_perm[32768][768]
// (lives in d_out), row = eBase[e] + rowi. 2-phase reg prefetch kept.
__global__ __launch_bounds__(256) void gemm_expert(
    const u16* __restrict__ A, const u16* __restrict__ Bt,
    __half* __restrict__ Cp, int N, int K, const float* __restrict__ bias,
    const int* __restrict__ counts, const int* __restrict__ eBase,
    const int* __restrict__ tokList, const float* __restrict__ wgtList) {
  __shared__ u16 As[128 * 64];
  __shared__ u16 Bs[128 * 64];
  const int did = blockIdx.x;
  const int e = did & 7;        // expert pinned to XCD
  const int s = did >> 3;       // 0..767 within expert
  const int bx = s % 6;         // n-block
  const int by = s / 6;         // m-panel (real work front-loaded per XCD)
  const int cnt = counts[e];
  const int m0 = by * 128, n0 = bx * 128;
  if (m0 >= cnt) return;
  const int tid = threadIdx.x;
  const int lane = tid & 63, wv = tid >> 6;
  const int wr = wv >> 1, wc = wv & 1;
  const int lm = lane & 15, lq = lane >> 4;
  const u16* Bte = Bt + (size_t)e * N * K;
  const int* tokl = tokList + e * TOKENS;
  const float* wl = wgtList + e * TOKENS;
  const float* biasE = bias + e * N;
  const int base0 = eBase[e];

  // hoisted staging geometry: thread stages A/B rows r0 + {0,32,64,96}
  const int r0 = tid >> 3, g = tid & 7;
  const int swz = (g ^ (r0 & 7)) << 3;  // (r0+i*32)&7 == r0&7
  const u16* ap[4];
  const u16* bp[4];
#pragma unroll
  for (int i = 0; i < 4; i++) {
    const int row = m0 + r0 + i * 32;
    const int tok = (row < cnt) ? tokl[row] : 0;
    ap[i] = A + (size_t)tok * K + g * 8;
    bp[i] = Bte + (size_t)(n0 + r0 + i * 32) * K + g * 8;
  }

  f32x4 acc[4][4];
  const f32x4 z4 = {0.f, 0.f, 0.f, 0.f};
#pragma unroll
  for (int i = 0; i < 4; i++)
#pragma unroll
    for (int j = 0; j < 4; j++) acc[i][j] = z4;

  // prologue: tile 0 -> regs -> LDS
  u32x4 pa[4], pb[4];
#pragma unroll
  for (int i = 0; i < 4; i++) {
    pa[i] = *(const u32x4*)(ap[i]);
    pb[i] = *(const u32x4*)(bp[i]);
  }
#pragma unroll
  for (int i = 0; i < 4; i++) {
    *(u32x4*)(&As[(r0 + i * 32) * 64 + swz]) = pa[i];
    *(u32x4*)(&Bs[(r0 + i * 32) * 64 + swz]) = pb[i];
  }

  for (int k0 = 0; k0 < K; k0 += 64) {
    __syncthreads();  // LDS tile k0 ready
    const bool more = (k0 + 64) < K;
    if (more) {
#pragma unroll
      for (int i = 0; i < 4; i++) {
        pa[i] = *(const u32x4*)(ap[i] + k0 + 64);
        pb[i] = *(const u32x4*)(bp[i] + k0 + 64);
      }
    }
#pragma unroll
    for (int kx = 0; kx < 8; kx += 4) {
      bf16x8 af[4], bfv[4];
#pragma unroll
      for (int i = 0; i < 4; i++) {
        const int ra = wr * 64 + i * 16 + lm;
        af[i] = *(const bf16x8*)(&As[ra * 64 + (((ra & 7) ^ (kx + lq)) << 3)]);
        const int rb = wc * 64 + i * 16 + lm;
        bfv[i] = *(const bf16x8*)(&Bs[rb * 64 + (((rb & 7) ^ (kx + lq)) << 3)]);
      }
#pragma unroll
      for (int i = 0; i < 4; i++)
#pragma unroll
        for (int j = 0; j < 4; j++)
          acc[i][j] = mfma_bf(af[i], bfv[j], acc[i][j]);
    }
    __syncthreads();  // all waves done reading LDS tile k0
    if (more) {
#pragma unroll
      for (int i = 0; i < 4; i++) {
        *(u32x4*)(&As[(r0 + i * 32) * 64 + swz]) = pa[i];
        *(u32x4*)(&Bs[(r0 + i * 32) * 64 + swz]) = pb[i];
      }
    }
  }
#pragma unroll
  for (int i = 0; i < 4; i++)
#pragma unroll
    for (int r = 0; r < 4; r++) {
      const int rowi = m0 + wr * 64 + i * 16 + lq * 4 + r;
      const bool live = (rowi < cnt);
      const float w = live ? wl[rowi] : 0.f;
      const size_t prow = live ? (size_t)(base0 + rowi) * (size_t)N : 0;
#pragma unroll
      for (int j = 0; j < 4; j++) {
        const int col = n0 + wc * 64 + j * 16 + lm;
        const float v = (acc[i][j][r] + biasE[col]) * w;
        // pair lanes: even lm stores (col, col+1) as one __half2
        const float vn = __shfl_xor(v, 1);
        if (live && (lm & 1) == 0) {
          *(__half2*)(Cp + prow + col) =
              __halves2half2(__float2half(v), __float2half(vn));
        }
      }
    }
}

// -------------------------------------------------- router (all fp32)
__global__ __launch_bounds__(256) void router_kernel(
    const float* __restrict__ x2, const float* __restrict__ g2,
    const float* __restrict__ b2, const float* __restrict__ rw,
    const float* __restrict__ rb, const float* __restrict__ rlng,
    const float* __restrict__ rlnb, const float* __restrict__ noise,
    int* __restrict__ eidx, float* __restrict__ ewgt) {
  const int token = blockIdx.x * 4 + (threadIdx.x >> 6);
  const int lane = threadIdx.x & 63;
  const size_t base = (size_t)token * CDIM;
  float v[12];
  float s = 0.f, ss = 0.f;
#pragma unroll
  for (int j = 0; j < 12; j++) {
    const int idx = lane + j * 64;
    v[j] = x2[base + idx];
    s += v[j];
    ss += v[j] * v[j];
  }
#pragma unroll
  for (int m = 1; m < 64; m <<= 1) {
    s += __shfl_xor(s, m);
    ss += __shfl_xor(ss, m);
  }
  const float mean = s * (1.f / CDIM);
  const float var = ss * (1.f / CDIM) - mean * mean;
  const float rs = rsqrtf(var + 1e-5f);

  float acc[8];
#pragma unroll
  for (int e = 0; e < 8; e++) acc[e] = 0.f;
#pragma unroll
  for (int j = 0; j < 12; j++) {
    const int d = lane + j * 64;
    const float hv = (v[j] - mean) * rs * g2[d] + b2[d];
    const f32x4 w0v = *(const f32x4*)(rw + (size_t)d * 8);
    const f32x4 w1v = *(const f32x4*)(rw + (size_t)d * 8 + 4);
#pragma unroll
    for (int e = 0; e < 4; e++) {
      acc[e] += hv * w0v[e];
      acc[e + 4] += hv * w1v[e];
    }
  }
#pragma unroll
  for (int m = 1; m < 64; m <<= 1)
#pragma unroll
    for (int e = 0; e < 8; e++) acc[e] += __shfl_xor(acc[e], m);

  float y[8];
  float emean = 0.f;
#pragma unroll
  for (int e = 0; e < 8; e++) {
    y[e] = acc[e] + rb[e];
    emean += y[e];
  }
  emean *= 0.125f;
  float evar = 0.f;
#pragma unroll
  for (int e = 0; e < 8; e++) {
    const float d = y[e] - emean;
    evar += d * d;
  }
  evar *= 0.125f;
  const float ers = rsqrtf(evar + 1e-5f);
  float lg[8];
  float mx = -1e30f;
#pragma unroll
  for (int e = 0; e < 8; e++) {
    lg[e] = (y[e] - emean) * ers * rlng[e] + rlnb[e];
    mx = fmaxf(mx, lg[e]);
  }
  float se = 0.f;
#pragma unroll
  for (int e = 0; e < 8; e++) {
    lg[e] = expf(lg[e] - mx);
    se += lg[e];
  }
  const float inv = 1.f / se;
  float r2[8];
#pragma unroll
  for (int e = 0; e < 8; e++)
    r2[e] = lg[e] * inv + noise[(size_t)token * 8 + e] * 0.125f;

  int e0 = 0;
  float v0 = r2[0];
#pragma unroll
  for (int e = 1; e < 8; e++)
    if (r2[e] > v0) {
      v0 = r2[e];
      e0 = e;
    }
  int e1 = -1;
  float v1 = -1e30f;
#pragma unroll
  for (int e = 0; e < 8; e++)
    if (e != e0 && r2[e] > v1) {
      v1 = r2[e];
      e1 = e;
    }
  const float w0 = 1.f / (1.f + expf(v1 - v0));
  if (lane == 0) {
    eidx[token * 2] = e0;
    eidx[token * 2 + 1] = e1;
    ewgt[token * 2] = w0;
    ewgt[token * 2 + 1] = 1.f - w0;
  }
}

// -------------------------------------------------- lists (+ inverse pos map)
__global__ __launch_bounds__(256) void build_lists(
    const int* __restrict__ eidx, const float* __restrict__ ewgt,
    int* __restrict__ counts, int* __restrict__ tokL, float* __restrict__ wgtL,
    int* __restrict__ posL) {
  const int e = blockIdx.x;
  __shared__ int cnt;
  if (threadIdx.x == 0) cnt = 0;
  __syncthreads();
  const int lane = threadIdx.x & 63;
  for (int t = threadIdx.x; t < TOKENS; t += 256) {
#pragma unroll
    for (int k = 0; k < 2; k++) {
      const bool match = (eidx[t * 2 + k] == e);
      const unsigned long long mb = __ballot(match);
      if (mb) {
        const int leader = __ffsll((unsigned long long)mb) - 1;
        int base = 0;
        if (lane == leader) base = atomicAdd(&cnt, __popcll(mb));
        base = __shfl(base, leader);
        if (match) {
          const int rank = __popcll(mb & ((1ull << lane) - 1ull));
          tokL[e * TOKENS + base + rank] = t;
          wgtL[e * TOKENS + base + rank] = ewgt[t * 2 + k];
          posL[t * 2 + k] = base + rank;
        }
      }
    }
  }
  __syncthreads();
  if (threadIdx.x == 0) counts[e] = cnt;
}

// -------------------------------------------------- prefix over 8 counts
__global__ void prefix_counts(const int* __restrict__ counts,
                              int* __restrict__ eBase) {
  if (threadIdx.x == 0) {
    int s = 0;
#pragma unroll
    for (int e = 0; e < NEXP; e++) {
      eBase[e] = s;
      s += counts[e];
    }
    eBase[NEXP] = s;
  }
}

// -------------------------------------------------- combine: x2 += moe rows
__global__ __launch_bounds__(256) void combine_moe(
    float* __restrict__ x2, const __half* __restrict__ Cp,
    const int* __restrict__ eidx, const int* __restrict__ posL,
    const int* __restrict__ eBase) {
  const int t = blockIdx.x * 4 + (threadIdx.x >> 6);
  const int lane = threadIdx.x & 63;
  const int e0 = eidx[t * 2], e1 = eidx[t * 2 + 1];
  const size_t q0 = (size_t)(eBase[e0] + posL[t * 2]) * CDIM;
  const size_t q1 = (size_t)(eBase[e1] + posL[t * 2 + 1]) * CDIM;
  const size_t base = (size_t)t * CDIM;
#pragma unroll
  for (int j = 0; j < 12; j++) {
    const int d = lane + j * 64;
    const float m =
        __half2float(Cp[q0 + d]) + __half2float(Cp[q1 + d]);
    x2[base + d] += m;
  }
}

// -------------------------------------------------- copy
__global__ __launch_bounds__(256) void copy_f32(const float* __restrict__ in,
                                                float* __restrict__ out) {
  const int i = (blockIdx.x * 256 + threadIdx.x) * 4;
  *(float4*)(out + i) = *(const float4*)(in + i);
}

// -------------------------------------------------- launch
extern "C" void kernel_launch(void* const* d_in, const int* in_sizes, int n_in,
                              void* d_out, int out_size, void* d_ws,
                              size_t ws_size, hipStream_t stream) {
  const float* x = (const float*)d_in[0];
  const float* noise = (const float*)d_in[1];
  const float* ln1_g = (const float*)d_in[2];
  const float* ln1_b = (const float*)d_in[3];
  const float* qkv_w = (const float*)d_in[4];
  const float* proj_w = (const float*)d_in[5];
  const float* proj_b = (const float*)d_in[6];
  const float* ln2_g = (const float*)d_in[7];
  const float* ln2_b = (const float*)d_in[8];
  const float* route_w = (const float*)d_in[9];
  const float* route_b = (const float*)d_in[10];
  const float* rln_g = (const float*)d_in[11];
  const float* rln_b = (const float*)d_in[12];
  const float* expert_w = (const float*)d_in[13];
  const float* expert_b = (const float*)d_in[14];

  char* ws = (char*)d_ws;
  // [0, 50331648)            x2f fp32 (residual + accumulation target)
  // [50331648, 88080384)     qkv split planes for the active quarter:
  //   qkh  [4096][1536] f16  @ +50331648  (12582912 B)  Q|K hi
  //   qkl  [4096][1536] f16  @ +62914560  (12582912 B)  Q|K lo
  //   vIq  [4096][768]  u32  @ +75497472  (12582912 B)  V hi|lo packed
  // post-attn this region is reused for exp_wt + h2 + lists
  float* x2f = (float*)(ws);
  f16* qkh = (f16*)(ws + 50331648);
  f16* qkl = (f16*)(ws + 62914560);
  u32* vIq = (u32*)(ws + 75497472);
  u16* exp_wt = (u16*)(ws + 50331648);    // 9437184 (post-attn)
  u16* h2 = (u16*)(ws + 59768832);        // 25165824 (post-attn)
  int* counts = (int*)(ws + 84934656);    // 64
  int* eBase = (int*)(ws + 84934784);     // 64 (within counts' 256-B slot)
  int* eidx = (int*)(ws + 84934912);      // 131072
  float* ewgt = (float*)(ws + 85065984);  // 131072
  int* tokL = (int*)(ws + 85197056);      // 524288
  float* wgtL = (float*)(ws + 85721344);  // 524288
  int* posL = (int*)(ws + 86245632);      // 131072 -> end 86376704
  // weight f16 planes (persist until proj gemm; disjoint from qkv region)
  f16* qkvw_h = (f16*)(ws + 88080384);    // 3538944
  f16* qkvw_l = (f16*)(ws + 91619328);    // 3538944
  f16* projw_h = (f16*)(ws + 95158272);   // 1179648
  f16* projw_l = (f16*)(ws + 96337920);   // 1179648  -> end 97517568
  // h1f (post-LN1) and attention output ping-pong through d_out (fp32).
  // Post-proj, d_out is reused as C_perm: 32768 x 768 f16 = out_size exactly.
  float* h1f = (float*)d_out;
  __half* cperm = (__half*)d_out;

  const dim3 blk(256);
  transpose_split_f16<<<dim3(36, 12), blk, 0, stream>>>(qkv_w, qkvw_h, qkvw_l,
                                                        768, 2304);
  transpose_split_f16<<<dim3(12, 12), blk, 0, stream>>>(proj_w, projw_h,
                                                        projw_l, 768, 768);
  ln_rows<false><<<dim3(4096), blk, 0, stream>>>(x, ln1_g, ln1_b, h1f);
  for (int q = 0; q < 4; q++) {
    gemm_f16s<2><<<dim3(18, 32), blk, 0, stream>>>(
        h1f + (size_t)q * 4096 * 768, qkvw_h, qkvw_l, nullptr, 4096, 2304,
        768, nullptr, nullptr, qkh, qkl, vIq);
    attn_f16s<<<dim3(16, 12, 4), blk, 0, stream>>>(qkh, qkl, vIq, h1f, q);
  }
  gemm_f16s<1><<<dim3(6, 128), blk, 0, stream>>>(h1f, projw_h, projw_l, x2f,
                                                 16384, 768, 768, proj_b, x,
                                                 nullptr, nullptr, nullptr);
  ln_rows<true><<<dim3(4096), blk, 0, stream>>>(x2f, ln2_g, ln2_b, h2);
  transpose_f32_bf16<<<dim3(12, 12, 8), blk, 0, stream>>>(expert_w, exp_wt,
                                                          768, 768);
  router_kernel<<<dim3(4096), blk, 0, stream>>>(x2f, ln2_g, ln2_b, route_w,
                                                route_b, rln_g, rln_b, noise,
                                                eidx, ewgt);
  build_lists<<<dim3(8), blk, 0, stream>>>(eidx, ewgt, counts, tokL, wgtL,
                                           posL);
  prefix_counts<<<dim3(1), dim3(64), 0, stream>>>(counts, eBase);
  gemm_expert<<<dim3(6144), blk, 0, stream>>>(h2, exp_wt, cperm, 768, 768,
                                              expert_b, counts, eBase, tokL,
                                              wgtL);
  combine_moe<<<dim3(4096), blk, 0, stream>>>(x2f, cperm, eidx, posL, eBase);
  copy_f32<<<dim3(12288), blk, 0, stream>>>(x2f, (float*)d_out);
}